// Round 22
// baseline (878.743 us; speedup 1.0000x reference)
//
#include <hip/hip_runtime.h>

// ---------- types & helpers ----------
typedef short short8 __attribute__((ext_vector_type(8)));
typedef _Float16 h8 __attribute__((ext_vector_type(8)));
typedef float f32x4 __attribute__((ext_vector_type(4)));

#define DEVI __device__ __forceinline__

DEVI float h2f(short s) { return (float)__builtin_bit_cast(_Float16, s); }
DEVI short f2h(float f) { return __builtin_bit_cast(short, (_Float16)f); }
DEVI f32x4 mfma16(short8 a, short8 b, f32x4 c) {
  return __builtin_amdgcn_mfma_f32_16x16x32_f16(
      __builtin_bit_cast(h8, a), __builtin_bit_cast(h8, b), c, 0, 0, 0);
}

// ---------- DPP 64-lane reductions (gfx9 pattern), result broadcast ----------
DEVI float wave_max_bcast(float v) {
  const int ID = 0xff800000;  // -inf
  int x = __builtin_bit_cast(int, v);
#define STEPM(ctrl)                                                     \
  {                                                                     \
    int t = __builtin_amdgcn_update_dpp(ID, x, ctrl, 0xf, 0xf, false);  \
    x = __builtin_bit_cast(int, fmaxf(__builtin_bit_cast(float, x),     \
                                      __builtin_bit_cast(float, t)));   \
  }
  STEPM(0x111) STEPM(0x112) STEPM(0x114) STEPM(0x118) STEPM(0x142) STEPM(0x143)
#undef STEPM
  return __builtin_bit_cast(float, __builtin_amdgcn_readlane(x, 63));
}
DEVI float wave_min_bcast_f(float v) {
  const int ID = 0x7f800000;  // +inf
  int x = __builtin_bit_cast(int, v);
#define STEPN(ctrl)                                                     \
  {                                                                     \
    int t = __builtin_amdgcn_update_dpp(ID, x, ctrl, 0xf, 0xf, false);  \
    x = __builtin_bit_cast(int, fminf(__builtin_bit_cast(float, x),     \
                                      __builtin_bit_cast(float, t)));   \
  }
  STEPN(0x111) STEPN(0x112) STEPN(0x114) STEPN(0x118) STEPN(0x142) STEPN(0x143)
#undef STEPN
  return __builtin_bit_cast(float, __builtin_amdgcn_readlane(x, 63));
}
DEVI unsigned wave_min_bcast_u(unsigned v) {
  const int ID = (int)0xffffffff;
  int x = (int)v;
#define STEPU(ctrl)                                                     \
  {                                                                     \
    int t = __builtin_amdgcn_update_dpp(ID, x, ctrl, 0xf, 0xf, false);  \
    x = (int)((unsigned)x < (unsigned)t ? (unsigned)x : (unsigned)t);   \
  }
  STEPU(0x111) STEPU(0x112) STEPU(0x114) STEPU(0x118) STEPU(0x142) STEPU(0x143)
#undef STEPU
  return (unsigned)__builtin_amdgcn_readlane(x, 63);
}
// inclusive add-scan across 64 lanes (gfx9 dpp scan pattern)
DEVI unsigned wave_iscan_add(unsigned v) {
  int x = (int)v, t;
  t = __builtin_amdgcn_update_dpp(0, x, 0x111, 0xf, 0xf, false); x += t;
  t = __builtin_amdgcn_update_dpp(0, x, 0x112, 0xf, 0xf, false); x += t;
  t = __builtin_amdgcn_update_dpp(0, x, 0x114, 0xf, 0xf, false); x += t;
  t = __builtin_amdgcn_update_dpp(0, x, 0x118, 0xf, 0xf, false); x += t;
  t = __builtin_amdgcn_update_dpp(0, x, 0x142, 0xa, 0xf, false); x += t;
  t = __builtin_amdgcn_update_dpp(0, x, 0x143, 0xc, 0xf, false); x += t;
  return (unsigned)x;
}

// ---------- weight prep: f16 casts + folded W'' = [w1a | w1b - w1a] ----------
__global__ __launch_bounds__(256) void prep_kernel(
    const float* __restrict__ w2, const float* __restrict__ s1w2,
    const float* __restrict__ s2w2, const float* __restrict__ s1w1,
    const float* __restrict__ s2w1, short* __restrict__ w2b,
    short* __restrict__ s1w2b, short* __restrict__ s2w2b,
    short* __restrict__ W1pp, short* __restrict__ W2pp) {
  int i = blockIdx.x * 256 + threadIdx.x;
  if (i < 4096) {
    w2b[i] = f2h(w2[i]);
  } else if (i < 20480) {
    int j = i - 4096; s1w2b[j] = f2h(s1w2[j]);
  } else if (i < 86016) {
    int j = i - 20480; s2w2b[j] = f2h(s2w2[j]);
  } else if (i < 102400) {
    int j = i - 86016; int c = j & 127;
    float v = s1w1[j]; if (c >= 64) v -= s1w1[j - 64];
    W1pp[j] = f2h(v);
  } else if (i < 167936) {
    int j = i - 102400; int c = j & 255;
    float v = s2w1[j]; if (c >= 128) v -= s2w1[j - 128];
    W2pp[j] = f2h(v);
  }
}

// ---------- stage A: xyz transpose + h0 = x @ w1^T (K=3, VALU fp32) ----------
__global__ __launch_bounds__(256) void stageA_kernel(
    const float* __restrict__ x, const float* __restrict__ w1,
    float* __restrict__ xyz, short* __restrict__ h0) {
  int i = blockIdx.x * 256 + threadIdx.x;  // b*4096 + n, < 131072
  int b = i >> 12, n = i & 4095;
  const float* xb = x + ((size_t)b * 3 << 12) + n;
  float x0 = xb[0], x1 = xb[4096], x2 = xb[8192];
  float* xp = xyz + (size_t)i * 3;
  xp[0] = x0; xp[1] = x1; xp[2] = x2;
  short* hp = h0 + ((size_t)i << 6);
#pragma unroll
  for (int o8 = 0; o8 < 8; ++o8) {
    short8 t;
#pragma unroll
    for (int j = 0; j < 8; ++j) {
      int o = o8 * 8 + j;
      float h = x0 * w1[o * 3] + x1 * w1[o * 3 + 1] + x2 * w1[o * 3 + 2];
      t[j] = f2h(h);
    }
    *reinterpret_cast<short8*>(hp + o8 * 8) = t;
  }
}

// ---------- companion bodies ----------

DEVI void stats64_body(int bid, int nb, int tid, const short* __restrict__ h,
                       float* __restrict__ partials, int M) {
  __shared__ float l0[256], l1[256];
  const int c = tid & 63, g = tid >> 6;
  float s0 = 0.f, s1 = 0.f;
  for (int m = bid * 4 + g; m < M; m += nb * 4) {
    float v = h2f(h[(size_t)m * 64 + c]);
    s0 += v; s1 += v * v;
  }
  l0[tid] = s0; l1[tid] = s1;
  __syncthreads();
  if (g == 0) {
    for (int w = 1; w < 4; ++w) { s0 += l0[c + w * 64]; s1 += l1[c + w * 64]; }
    partials[(size_t)c * nb + bid] = s0;
    partials[(size_t)(64 + c) * nb + bid] = s1;
  }
}

DEVI void reduce2_body(int c, int tid, const float* __restrict__ partials,
                       const float* __restrict__ gamma, const float* __restrict__ beta,
                       float* __restrict__ scale, float* __restrict__ shift,
                       int NB, int C, float invM) {
  __shared__ float l0[4], l1[4];
  const float* p0 = partials + (size_t)c * NB;
  const float* p1 = partials + (size_t)(C + c) * NB;
  float s0 = 0.f, s1 = 0.f;
  for (int i = tid; i < NB; i += 256) { s0 += p0[i]; s1 += p1[i]; }
#pragma unroll
  for (int off = 1; off < 64; off <<= 1) {
    s0 += __shfl_xor(s0, off);
    s1 += __shfl_xor(s1, off);
  }
  if ((tid & 63) == 0) { l0[tid >> 6] = s0; l1[tid >> 6] = s1; }
  __syncthreads();
  if (tid == 0) {
    s0 = l0[0] + l0[1] + l0[2] + l0[3];
    s1 = l1[0] + l1[1] + l1[2] + l1[3];
    float mean = s0 * invM;
    float var = fmaxf(s1 * invM - mean * mean, 0.f);
    float sc = gamma[c] / sqrtf(var + 1e-5f);
    scale[c] = sc;
    shift[c] = beta[c] - mean * sc;
  }
}

__global__ __launch_bounds__(256) void reduce2_kernel(
    const float* __restrict__ partials, const float* __restrict__ gamma,
    const float* __restrict__ beta, float* __restrict__ scale,
    float* __restrict__ shift, int NB, int C, float invM) {
  reduce2_body(blockIdx.x, threadIdx.x, partials, gamma, beta, scale, shift, NB, C, invM);
}

// BN+ReLU apply, 8 f16/thread (C=64 tensors)
DEVI void apply_body(int bid, int tid, const short* __restrict__ h,
                     short* __restrict__ f, const float* __restrict__ scale,
                     const float* __restrict__ shift) {
  size_t i = ((size_t)bid * 256 + tid) * 8;
  int c0 = (int)(i & 63);
  short8 v = *reinterpret_cast<const short8*>(h + i);
  short8 o;
#pragma unroll
  for (int j = 0; j < 8; ++j) {
    float y = h2f(v[j]) * scale[c0 + j] + shift[c0 + j];
    o[j] = f2h(fmaxf(y, 0.f));
  }
  *reinterpret_cast<short8*>(f + i) = o;
}

// ---------- FPS body, segmented; exact numpy semantics ----------
template <int NPTS, int T>
DEVI void fps_seg_body(char* smemraw, int bid, int tid, const float* __restrict__ xyz,
                       int* __restrict__ out, float* __restrict__ xyzc, int nsel,
                       int it0, int it1, float* __restrict__ dming,
                       int* __restrict__ farg) {
  __builtin_amdgcn_s_setprio(1);
  constexpr int PT = NPTS / T;
  constexpr int NW = T / 64;
  float* sx = (float*)smemraw;
  float* sy = sx + NPTS;
  float* sz = sy + NPTS;
  float* wv = sz + NPTS;                    // [2][NW]
  unsigned* wi = (unsigned*)(wv + 2 * NW);  // [2][NW]
  const int lane = tid & 63, wave = tid >> 6;
  const float* base = xyz + (size_t)bid * NPTS * 3;
  float px[PT], py[PT], pz[PT], dmin[PT];
#pragma unroll
  for (int j = 0; j < PT; ++j) {
    int n = j * T + tid;
    px[j] = base[n * 3]; py[j] = base[n * 3 + 1]; pz[j] = base[n * 3 + 2];
    sx[n] = px[j]; sy[n] = py[j]; sz[n] = pz[j];
  }
  int far;
  if (it0 == 0) {
#pragma unroll
    for (int j = 0; j < PT; ++j) dmin[j] = 1e10f;
    far = 0;
  } else {
#pragma unroll
    for (int j = 0; j < PT; ++j) dmin[j] = dming[(size_t)bid * NPTS + j * T + tid];
    far = farg[bid];
  }
  __syncthreads();
  float cx = sx[far], cy = sy[far], cz = sz[far];
  for (int it = it0; it < it1; ++it) {
    if (tid == 0) {
      out[bid * nsel + it] = far;
      if (xyzc) {
        float* xc = xyzc + ((size_t)bid * nsel + it) * 3;
        xc[0] = cx; xc[1] = cy; xc[2] = cz;
      }
    }
    float bv = -1.f;
#pragma unroll
    for (int j = 0; j < PT; ++j) {
      float dx = __fsub_rn(px[j], cx), dy = __fsub_rn(py[j], cy), dz = __fsub_rn(pz[j], cz);
      float d = __fadd_rn(__fadd_rn(__fmul_rn(dx, dx), __fmul_rn(dy, dy)), __fmul_rn(dz, dz));
      float dm = fminf(dmin[j], d);
      dmin[j] = dm;
      bv = fmaxf(bv, dm);
    }
    float wmv = wave_max_bcast(bv);
    unsigned ci = 0xffffffffu;  // rescan, descending j -> smallest index kept
#pragma unroll
    for (int j = PT - 1; j >= 0; --j)
      if (dmin[j] == wmv) ci = (unsigned)(j * T + tid);
    unsigned wmi = wave_min_bcast_u(ci);
    const int bsel = it & 1;
    if (lane == 0) { wv[bsel * NW + wave] = wmv; wi[bsel * NW + wave] = wmi; }
    __syncthreads();
    const int e = lane & (NW - 1);
    float v = wv[bsel * NW + e];
    unsigned si = wi[bsel * NW + e];
#define CMB(ctrl)                                                                        \
  {                                                                                      \
    float v2 = __builtin_bit_cast(                                                       \
        float, __builtin_amdgcn_update_dpp(0, __builtin_bit_cast(int, v), ctrl, 0xf, 0xf, true)); \
    unsigned i2 = (unsigned)__builtin_amdgcn_update_dpp(0, (int)si, ctrl, 0xf, 0xf, true);\
    bool bt = (v2 > v) || (v2 == v && i2 < si);                                          \
    v = bt ? v2 : v; si = bt ? i2 : si;                                                  \
  }
    if constexpr (NW >= 2) CMB(0x121)   // row_ror:1
    if constexpr (NW >= 4) CMB(0x122)   // row_ror:2
    if constexpr (NW >= 8) CMB(0x124)   // row_ror:4
#undef CMB
    far = (int)si;
    cx = sx[far]; cy = sy[far]; cz = sz[far];  // broadcast LDS read, once/iter
  }
  if (it1 < nsel) {
#pragma unroll
    for (int j = 0; j < PT; ++j) dming[(size_t)bid * NPTS + j * T + tid] = dmin[j];
    if (tid == 0) farg[bid] = far;
  }
}

// ---------- kNN: exact top-32 SET via 4096-bucket histogram ----------
#define KNN_SMEM_BYTES ((4096 + 256 + 4 + 256 + 256) * 4)
template <int NPTS, int S>
DEVI void knn_body(char* smemraw, int bs, int tid, const float* __restrict__ pts,
                   const int* __restrict__ fpsidx, int* __restrict__ knn) {
  constexpr int PT = NPTS / 256;
  unsigned* hist = (unsigned*)smemraw;
  unsigned* csums = hist + 4096;
  unsigned* meta = csums + 256;   // 0: below-counter, 1: B, 2: cb, 3: boundary-counter
  float* bval = (float*)(meta + 4);
  unsigned* bidx = (unsigned*)(bval + 256);
  const int lane = tid & 63, wave = tid >> 6;
  const int b = bs / S;
  const int cidx = fpsidx[bs];
  const float* cp = pts + ((size_t)b * NPTS + cidx) * 3;
  const float qx = cp[0], qy = cp[1], qz = cp[2];
  const float qq = __fadd_rn(__fadd_rn(__fmul_rn(qx, qx), __fmul_rn(qy, qy)), __fmul_rn(qz, qz));
  const float* base = pts + (size_t)b * NPTS * 3;
  float d[PT]; unsigned u[PT];
#pragma unroll
  for (int j = 0; j < PT; ++j) {
    int n = j * 256 + tid;
    float x = base[n * 3], y = base[n * 3 + 1], z = base[n * 3 + 2];
    float pp = __fadd_rn(__fadd_rn(__fmul_rn(x, x), __fmul_rn(y, y)), __fmul_rn(z, z));
    float dot = __fadd_rn(__fadd_rn(__fmul_rn(qx, x), __fmul_rn(qy, y)), __fmul_rn(qz, z));
    d[j] = __fsub_rn(__fadd_rn(qq, pp), __fmul_rn(2.f, dot));
    unsigned bits = __builtin_bit_cast(unsigned, d[j]);
    unsigned m = (unsigned)((int)bits >> 31);
    u[j] = bits ^ (m | 0x80000000u);
  }
  {
    uint4 z4 = {0u, 0u, 0u, 0u};
    uint4* hq = (uint4*)hist;
    for (int i = tid; i < 1024; i += 256) hq[i] = z4;
    if (tid == 0) { meta[0] = 0; meta[3] = 0; }
  }
  __syncthreads();
#pragma unroll
  for (int j = 0; j < PT; ++j) atomicAdd(&hist[u[j] >> 20], 1u);
  __syncthreads();
  {
    const uint4* hq = (const uint4*)(hist + tid * 16);
    unsigned cs = 0;
#pragma unroll
    for (int q = 0; q < 4; ++q) {
      uint4 v = hq[q];
      cs += v.x + v.y + v.z + v.w;
    }
    csums[tid] = cs;
  }
  __syncthreads();
  if (wave == 0) {
    const int t4 = lane * 4;
    unsigned c0 = csums[t4], c1 = csums[t4 + 1], c2 = csums[t4 + 2], c3 = csums[t4 + 3];
    unsigned lt = c0 + c1 + c2 + c3;
    unsigned incl = wave_iscan_add(lt);
    unsigned excl = incl - lt;
    unsigned long long blt = __ballot(incl >= 32u);
    int L = __ffsll((long long)blt) - 1;
    if (lane == L) {
      unsigned cum = excl;
      int bucket = -1;
      unsigned cc[4] = {c0, c1, c2, c3};
#pragma unroll
      for (int q = 0; q < 4; ++q) {
        if (bucket < 0 && cum + cc[q] >= 32u) {
          int bbase = (t4 + q) * 16;
          for (int h = 0; h < 16; ++h) {
            unsigned hv = hist[bbase + h];
            if (cum + hv >= 32u) { bucket = bbase + h; break; }
            cum += hv;
          }
        } else if (bucket < 0) {
          cum += cc[q];
        }
      }
      meta[1] = (unsigned)bucket;
      meta[2] = cum;
    }
  }
  __syncthreads();
  const unsigned B = meta[1];
  const unsigned cb = meta[2];
  int* kout = knn + (size_t)bs * 32;
#pragma unroll
  for (int j = 0; j < PT; ++j) {
    unsigned bk = u[j] >> 20;
    if (bk < B) {
      unsigned p = atomicAdd(&meta[0], 1u);
      kout[p] = j * 256 + tid;
    } else if (bk == B) {
      unsigned p = atomicAdd(&meta[3], 1u);
      if (p < 256u) { bval[p] = d[j]; bidx[p] = (unsigned)(j * 256 + tid); }
    }
  }
  __syncthreads();
  const int m = 32 - (int)cb;
  if (wave == 0 && m > 0) {
    unsigned nb = meta[3]; if (nb > 256u) nb = 256u;
    float v0 = (lane < (int)nb) ? bval[lane] : 3.4e38f;
    unsigned i0 = (lane < (int)nb) ? bidx[lane] : 0xffffffffu;
    float v1 = (lane + 64 < (int)nb) ? bval[lane + 64] : 3.4e38f;
    unsigned i1 = (lane + 64 < (int)nb) ? bidx[lane + 64] : 0xffffffffu;
    float v2 = (lane + 128 < (int)nb) ? bval[lane + 128] : 3.4e38f;
    unsigned i2 = (lane + 128 < (int)nb) ? bidx[lane + 128] : 0xffffffffu;
    float v3 = (lane + 192 < (int)nb) ? bval[lane + 192] : 3.4e38f;
    unsigned i3 = (lane + 192 < (int)nb) ? bidx[lane + 192] : 0xffffffffu;
    for (int k = 0; k < m; ++k) {
      float lv = v0; unsigned li = i0;
      if (v1 < lv || (v1 == lv && i1 < li)) { lv = v1; li = i1; }
      if (v2 < lv || (v2 == lv && i2 < li)) { lv = v2; li = i2; }
      if (v3 < lv || (v3 == lv && i3 < li)) { lv = v3; li = i3; }
      float wmv = wave_min_bcast_f(lv);
      unsigned ci = (lv == wmv) ? li : 0xffffffffu;
      unsigned wmi = wave_min_bcast_u(ci);
      if (lane == 0) kout[cb + k] = (int)wmi;
      if (i0 == wmi) { v0 = 3.4e38f; i0 = 0xffffffffu; }
      if (i1 == wmi) { v1 = 3.4e38f; i1 = 0xffffffffu; }
      if (i2 == wmi) { v2 = 3.4e38f; i2 = 0xffffffffu; }
      if (i3 == wmi) { v3 = 3.4e38f; i3 = 0xffffffffu; }
    }
  }
}

// ---------- MFMA GEMM with chunked W-staging + BN stat partials ----------
// EPI 0: store full h via LDS-transposed coalesced short8 stores.
// EPI 1: per-center (32-row) fp32 max/min epilogue (no h materialization);
//        exact because BN is affine: max relu(sc*h+sh) = relu(sc*(sc>=0?max:min)+sh).
// SBR: small-tile variant (BR=32, 4 waves share rows, 64-col slices, KC=32) —
//      halves the accumulator to 32 AGPR so 5 waves/SIMD fit (occupancy).
template <int KD, int ND, bool GATHER, bool BNA, int NPTS, int S, int EPI, bool SBR>
DEVI void gemm_body(char* smemraw, int bid, int tid, int gemmBlocks,
                    const short* A, const int* KNNp, const int* FPSp,
                    const short* __restrict__ W, const float* __restrict__ bnscale,
                    const float* __restrict__ bnshift, short* Hout,
                    float* __restrict__ mmax, float* __restrict__ mmin,
                    float* __restrict__ partials) {
  constexpr int C = KD / 2;
  constexpr int NT = SBR ? 4 : ((ND > 128) ? 8 : ND / 16);
  constexpr int BR = SBR ? 32 : ((ND > 128) ? 64 : 128);
  constexpr int KC = SBR ? 32 : ((ND >= 256) ? 64 : KD);  // staging chunk k-width
  constexpr int LOG2KC = (KC == 32) ? 5 : ((KC == 64) ? 6 : 7);
  constexpr int NCH = KD / KC;
  constexpr int KTC = KC / 32;
  constexpr int LROW = KC + 8;                    // +16B pad -> 2-way alias (free)
  constexpr int TROW = ND + 8;                    // epilogue tile pad
  constexpr int LBB = ND * LROW * 2;
  constexpr int TBB = BR * TROW * 2;
  constexpr int LSOFF = (LBB > TBB) ? LBB : TBB;
  short* lb = (short*)smemraw;                    // [ND][LROW]; reused as tile
  float* lstats = (float*)(smemraw + LSOFF);
  const int wave = tid >> 6, lane = tid & 63;
  const int rowOff = SBR ? 0 : ((ND > 128) ? (wave >> 1) * 32 : wave * 32);
  const int colOff = SBR ? wave * 64 : ((ND > 128) ? (wave & 1) * 128 : 0);
  const int mBase = bid * BR + rowOff;
  for (int i = tid; i < 2 * ND; i += 256) lstats[i] = 0.f;

  const short* aptr[2][2];
#pragma unroll
  for (int rg = 0; rg < 2; ++rg) {
    int m = mBase + rg * 16 + (lane & 15);
    if constexpr (GATHER) {
      int idx = KNNp[m];
      int bb = m / (S * 32);
      int s = (m - bb * (S * 32)) >> 5;
      int fidx = FPSp[bb * S + s];
      aptr[rg][0] = A + ((size_t)bb * NPTS + idx) * C;
      aptr[rg][1] = A + ((size_t)bb * NPTS + fidx) * C;
    } else {
      aptr[rg][0] = A + (size_t)m * KD;
      aptr[rg][1] = A + (size_t)m * KD + C;
    }
  }
  const int koLane = (lane >> 4) * 8;
  f32x4 acc[2][NT];
#pragma unroll
  for (int rg = 0; rg < 2; ++rg)
#pragma unroll
    for (int nt = 0; nt < NT; ++nt) acc[rg][nt] = (f32x4){0.f, 0.f, 0.f, 0.f};

#pragma unroll
  for (int ch = 0; ch < NCH; ++ch) {
    __syncthreads();
    constexpr int SIT = (ND * KC) / 2048;
#pragma unroll
    for (int i = 0; i < SIT; ++i) {
      int e = i * 2048 + tid * 8;
      int n = e >> LOG2KC, kk = e & (KC - 1);
      short8 v = *reinterpret_cast<const short8*>(W + (size_t)n * KD + ch * KC + kk);
      *reinterpret_cast<short8*>(&lb[n * LROW + kk]) = v;
    }
    __syncthreads();
#pragma unroll
    for (int ktc = 0; ktc < KTC; ++ktc) {
      const int kt = ch * KTC + ktc;
      const int half = (kt * 32 >= C) ? 1 : 0;
      const int ko = kt * 32 + koLane;
      const int koh = ko - half * C;
      short8 afrag[2];
#pragma unroll
      for (int rg = 0; rg < 2; ++rg) {
        short8 a = *reinterpret_cast<const short8*>(aptr[rg][half] + koh);
        if constexpr (BNA) {
          const float* scp = bnscale + ko;
          const float* shp = bnshift + ko;
#pragma unroll
          for (int j = 0; j < 8; ++j) {
            float v = h2f(a[j]);
            v = fmaxf(v * scp[j] + shp[j], 0.f);
            a[j] = f2h(v);
          }
        }
        afrag[rg] = a;
      }
#pragma unroll
      for (int nt = 0; nt < NT; ++nt) {
        short8 bfr = *reinterpret_cast<const short8*>(
            &lb[(colOff + nt * 16 + (lane & 15)) * LROW + ktc * 32 + koLane]);
        acc[0][nt] = mfma16(afrag[0], bfr, acc[0][nt]);
        acc[1][nt] = mfma16(afrag[1], bfr, acc[1][nt]);
      }
    }
  }
  __syncthreads();  // compute done: lb free, all A-reads retired

  // per-channel sum / sumsq partials (pre-BN stats of this layer's output)
#pragma unroll
  for (int nt = 0; nt < NT; ++nt) {
    float s0 = 0.f, s1 = 0.f;
#pragma unroll
    for (int rg = 0; rg < 2; ++rg)
#pragma unroll
      for (int i = 0; i < 4; ++i) {
        float v = acc[rg][nt][i];
        s0 += v; s1 += v * v;
      }
    s0 += __shfl_xor(s0, 16); s0 += __shfl_xor(s0, 32);
    s1 += __shfl_xor(s1, 16); s1 += __shfl_xor(s1, 32);
    if (lane < 16) {
      atomicAdd(&lstats[colOff + nt * 16 + lane], s0);
      atomicAdd(&lstats[ND + colOff + nt * 16 + lane], s1);
    }
  }

  if constexpr (EPI == 0) {
    // stage tile in LDS, then coalesced short8 stores
#pragma unroll
    for (int rg = 0; rg < 2; ++rg)
#pragma unroll
      for (int nt = 0; nt < NT; ++nt)
#pragma unroll
        for (int i = 0; i < 4; ++i) {
          int r = rowOff + rg * 16 + (lane >> 4) * 4 + i;
          int n = colOff + nt * 16 + (lane & 15);
          lb[r * TROW + n] = f2h(acc[rg][nt][i]);
        }
    __syncthreads();
    constexpr int TPR = ND / 8;       // threads per row
    constexpr int RPI = 256 / TPR;    // rows per iteration
    const int r0 = tid / TPR, c0 = (tid % TPR) * 8;
#pragma unroll
    for (int it = 0; it < BR / RPI; ++it) {
      int r = it * RPI + r0;
      short8 v = *reinterpret_cast<const short8*>(&lb[r * TROW + c0]);
      *reinterpret_cast<short8*>(&Hout[(size_t)(bid * BR + r) * ND + c0]) = v;
    }
  } else {
    // per-center max/min: waves jointly cover the center's 32 rows
    const int center = (bid * BR + rowOff) >> 5;
#pragma unroll
    for (int nt = 0; nt < NT; ++nt) {
      float mx = -3.4e38f, mn = 3.4e38f;
#pragma unroll
      for (int rg = 0; rg < 2; ++rg)
#pragma unroll
        for (int i = 0; i < 4; ++i) {
          float v = acc[rg][nt][i];
          mx = fmaxf(mx, v); mn = fminf(mn, v);
        }
      mx = fmaxf(mx, __shfl_xor(mx, 16)); mx = fmaxf(mx, __shfl_xor(mx, 32));
      mn = fminf(mn, __shfl_xor(mn, 16)); mn = fminf(mn, __shfl_xor(mn, 32));
      if (lane < 16) {
        mmax[(size_t)center * ND + colOff + nt * 16 + lane] = mx;
        mmin[(size_t)center * ND + colOff + nt * 16 + lane] = mn;
      }
    }
    __syncthreads();
  }
  for (int i = tid; i < 2 * ND; i += 256)
    partials[(size_t)i * gemmBlocks + bid] = lstats[i];
}

// ---------- fused wrappers ----------
// knn chunk mapping: 128 centers/chunk per batch; kb -> bs = (kb>>7)*S + s0 + (kb&127)

template <int FN, int FT>
__global__ __launch_bounds__(256, 1) void fps_stats_seg(
    int fpsBlocks, const float* fxyz, int* fout, float* fxyzc, int fnsel,
    int it0, int it1, float* dming, int* farg,
    const short* sh, float* sp, int sM, int snb) {
  extern __shared__ char smem[];
  if ((int)blockIdx.x < fpsBlocks)
    fps_seg_body<FN, FT>(smem, blockIdx.x, threadIdx.x, fxyz, fout, fxyzc, fnsel,
                         it0, it1, dming, farg);
  else
    stats64_body(blockIdx.x - fpsBlocks, snb, threadIdx.x, sh, sp, sM);
}

template <int FN, int FT, int KNPTS, int KS>
__global__ __launch_bounds__(256, 1) void fps_r2_knn_seg(
    int fpsBlocks, int compBlocks, const float* fxyz, int* fout, float* fxyzc,
    int fnsel, int it0, int it1, float* dming, int* farg,
    const float* partials, const float* gamma, const float* beta,
    float* scale, float* shift, int NB, int C, float invM,
    const float* kpts, const int* kfps, int* kout, int ks0) {
  extern __shared__ char smem[];
  const int bx = (int)blockIdx.x;
  if (bx < fpsBlocks) {
    fps_seg_body<FN, FT>(smem, bx, threadIdx.x, fxyz, fout, fxyzc, fnsel,
                         it0, it1, dming, farg);
  } else if (bx < fpsBlocks + compBlocks) {
    reduce2_body(bx - fpsBlocks, threadIdx.x, partials, gamma, beta, scale,
                 shift, NB, C, invM);
  } else {
    int kb = bx - fpsBlocks - compBlocks;
    int bs = (kb >> 7) * KS + ks0 + (kb & 127);
    knn_body<KNPTS, KS>(smem, bs, threadIdx.x, kpts, kfps, kout);
  }
}

template <int FN, int FT, int KD, int ND, bool BNA, int EPI, int KNPTS, int KS>
__global__ __launch_bounds__(256, 1) void fps_gemm_knn_seg(
    int fpsBlocks, int compBlocks, const float* fxyz, int* fout, float* fxyzc,
    int fnsel, int it0, int it1, float* dming, int* farg,
    const short* A, const short* W, const float* bnscale, const float* bnshift,
    short* Hout, float* partials,
    const float* kpts, const int* kfps, int* kout, int ks0) {
  extern __shared__ char smem[];
  const int bx = (int)blockIdx.x;
  if (bx < fpsBlocks) {
    fps_seg_body<FN, FT>(smem, bx, threadIdx.x, fxyz, fout, fxyzc, fnsel,
                         it0, it1, dming, farg);
  } else if (bx < fpsBlocks + compBlocks) {
    gemm_body<KD, ND, false, BNA, 1, 1, EPI, false>(smem, bx - fpsBlocks, threadIdx.x,
                                                    compBlocks, A, nullptr, nullptr,
                                                    W, bnscale, bnshift, Hout, nullptr,
                                                    nullptr, partials);
  } else {
    int kb = bx - fpsBlocks - compBlocks;
    int bs = (kb >> 7) * KS + ks0 + (kb & 127);
    knn_body<KNPTS, KS>(smem, bs, threadIdx.x, kpts, kfps, kout);
  }
}

// launch5: fps2 segA || last knn1 chunk || BN apply; full occupancy
template <int F2N, int NPTS, int S>
__global__ __launch_bounds__(256, 4) void fps2_knn_apply_kernel(
    int f2Blocks, const float* f2xyz, int* f2out, int f2nsel, int it0, int it1,
    float* dming2, int* farg2,
    int knnBlocks, const float* kpts, const int* kfps, int* kout, int ks0,
    const short* ah, short* af, const float* ascale, const float* ashift) {
  __shared__ __align__(16) char smem[KNN_SMEM_BYTES];
  const int bx = (int)blockIdx.x;
  if (bx < f2Blocks) {
    fps_seg_body<F2N, 256>(smem, bx, threadIdx.x, f2xyz, f2out, nullptr, f2nsel,
                           it0, it1, dming2, farg2);
  } else if (bx < f2Blocks + knnBlocks) {
    int kb = bx - f2Blocks;
    int bs = (kb >> 7) * S + ks0 + (kb & 127);
    knn_body<NPTS, S>(smem, bs, threadIdx.x, kpts, kfps, kout);
  } else {
    apply_body(bx - f2Blocks - knnBlocks, threadIdx.x, ah, af, ascale, ashift);
  }
}

// launch6: fps2 segB || SG1 gather gemm (XCD swizzle)
template <int F2N, int KD, int ND, int NPTS, int S>
__global__ __launch_bounds__(256, 4) void mega1_kernel(
    int f2Blocks, const float* f2xyz, int* f2out, int f2nsel, int it0, int it1,
    float* dming2, int* farg2,
    const short* A, const int* KNNp, const int* FPSp, const short* W,
    short* Hout, float* partials) {
  extern __shared__ char smem[];
  const int bx = (int)blockIdx.x;
  if (bx < f2Blocks) {
    fps_seg_body<F2N, 256>(smem, bx, threadIdx.x, f2xyz, f2out, nullptr, f2nsel,
                           it0, it1, dming2, farg2);
  } else {
    int gb = bx - f2Blocks;
    const int gB = (int)gridDim.x - f2Blocks;
    const int q = gB >> 3;
    gb = (gb & 7) * q + (gb >> 3);
    gemm_body<KD, ND, true, false, NPTS, S, 0, false>(smem, gb, threadIdx.x, gB, A,
                                                      KNNp, FPSp, W, nullptr, nullptr,
                                                      Hout, nullptr, nullptr, partials);
  }
}

// launch7: fps2 segC || SG1 gemm2 (in-place BNA, max/min epilogue)
template <int F2N, int KD, int ND>
__global__ __launch_bounds__(256, 4) void fps2_gemm_kernel(
    int f2Blocks, const float* f2xyz, int* f2out, int f2nsel, int it0, int it1,
    float* dming2, int* farg2,
    const short* A, const short* W, const float* bnscale, const float* bnshift,
    float* mmax, float* mmin, float* partials) {
  extern __shared__ char smem[];
  const int bx = (int)blockIdx.x;
  if (bx < f2Blocks) {
    fps_seg_body<F2N, 256>(smem, bx, threadIdx.x, f2xyz, f2out, nullptr, f2nsel,
                           it0, it1, dming2, farg2);
  } else {
    gemm_body<KD, ND, false, true, 1, 1, 1, false>(smem, bx - f2Blocks, threadIdx.x,
                                                   (int)gridDim.x - f2Blocks, A,
                                                   nullptr, nullptr, W, bnscale,
                                                   bnshift, nullptr, mmax, mmin,
                                                   partials);
  }
}

// standalone gemm; GATHER path gets bijective XCD swizzle (gridDim % 8 == 0)
template <int KD, int ND, bool GATHER, bool BNA, int NPTS, int S, int EPI>
__global__ __launch_bounds__(256, 4) void gemm_kernel(
    const short* A, const int* KNNp, const int* FPSp, const short* W,
    const float* bnscale, const float* bnshift, short* Hout,
    float* mmax, float* mmin, float* partials) {
  extern __shared__ char smem[];
  int bid = (int)blockIdx.x;
  if constexpr (GATHER) {
    const int q = (int)gridDim.x >> 3;
    bid = (bid & 7) * q + (bid >> 3);
  }
  gemm_body<KD, ND, GATHER, BNA, NPTS, S, EPI, false>(smem, bid, threadIdx.x,
                                                      gridDim.x, A, KNNp, FPSp, W,
                                                      bnscale, bnshift, Hout, mmax,
                                                      mmin, partials);
}

// small-tile gemm (SBR): 32 AGPR acc -> 5 waves/SIMD; BR=32, KC=32
template <int KD, int ND, bool GATHER, bool BNA, int NPTS, int S, int EPI>
__global__ __launch_bounds__(256, 5) void gemm_kernel5(
    const short* A, const int* KNNp, const int* FPSp, const short* W,
    const float* bnscale, const float* bnshift, short* Hout,
    float* mmax, float* mmin, float* partials) {
  extern __shared__ char smem[];
  int bid = (int)blockIdx.x;
  if constexpr (GATHER) {
    const int q = (int)gridDim.x >> 3;
    bid = (bid & 7) * q + (bid >> 3);
  }
  gemm_body<KD, ND, GATHER, BNA, NPTS, S, EPI, true>(smem, bid, threadIdx.x,
                                                     gridDim.x, A, KNNp, FPSp, W,
                                                     bnscale, bnshift, Hout, mmax,
                                                     mmin, partials);
}

// knn2 blocks first, then maxpool-f1 blocks (from mm1 max/min; 2 centers/block)
template <int NPTS, int S>
__global__ __launch_bounds__(256, 4) void maxpool_knn_kernel(
    int knnBlocks, const float* pts, const int* fpsidx, int* knn,
    const float* mmax, const float* mmin, const float* scale, const float* shift,
    short* f1) {
  __shared__ __align__(16) char smem[KNN_SMEM_BYTES];
  if ((int)blockIdx.x < knnBlocks) {
    knn_body<NPTS, S>(smem, blockIdx.x, threadIdx.x, pts, fpsidx, knn);
  } else {
    const int ctr = (blockIdx.x - knnBlocks) * 2 + (threadIdx.x >> 7);
    const int c = threadIdx.x & 127;
    const float sc = scale[c], sh = shift[c];
    float y = (sc >= 0.f) ? mmax[(size_t)ctr * 128 + c] : mmin[(size_t)ctr * 128 + c];
    f1[(size_t)ctr * 128 + c] = f2h(fmaxf(sc * y + sh, 0.f));
  }
}

// ---------- final: BN+ReLU on per-center max/min, transposed fp32 out ----------
__global__ __launch_bounds__(256) void maxpool_out_kernel(
    const float* __restrict__ mmax, const float* __restrict__ mmin,
    const float* __restrict__ scale, const float* __restrict__ shift,
    float* __restrict__ out) {
  const int bs = blockIdx.x, c = threadIdx.x;
  const int b = bs >> 8, s = bs & 255;
  const float sc = scale[c], sh = shift[c];
  float y = (sc >= 0.f) ? mmax[(size_t)bs * 256 + c] : mmin[(size_t)bs * 256 + c];
  out[((size_t)b << 16) + ((size_t)c << 8) + s] = fmaxf(sc * y + sh, 0.f);
}

// ---------- launch ----------
extern "C" void kernel_launch(void* const* d_in, const int* in_sizes, int n_in,
                              void* d_out, int out_size, void* d_ws, size_t ws_size,
                              hipStream_t stream) {
  (void)in_sizes; (void)n_in; (void)out_size; (void)ws_size;
  const float* x    = (const float*)d_in[0];
  const float* w1   = (const float*)d_in[1];
  const float* g1   = (const float*)d_in[2];
  const float* b1   = (const float*)d_in[3];
  const float* w2   = (const float*)d_in[4];
  const float* g2   = (const float*)d_in[5];
  const float* b2   = (const float*)d_in[6];
  const float* s1w1 = (const float*)d_in[7];
  const float* s1g1 = (const float*)d_in[8];
  const float* s1b1 = (const float*)d_in[9];
  const float* s1w2 = (const float*)d_in[10];
  const float* s1g2 = (const float*)d_in[11];
  const float* s1b2 = (const float*)d_in[12];
  const float* s2w1 = (const float*)d_in[13];
  const float* s2g1 = (const float*)d_in[14];
  const float* s2b1 = (const float*)d_in[15];
  const float* s2w2 = (const float*)d_in[16];
  const float* s2g2 = (const float*)d_in[17];
  const float* s2b2 = (const float*)d_in[18];
  float* out = (float*)d_out;

  char* ws = (char*)d_ws;
  size_t off = 0;
  auto alloc = [&](size_t bytes) -> char* {
    size_t p = (off + 255) & ~(size_t)255;
    off = p + bytes;
    return ws + p;
  };

  float* xyz      = (float*)alloc(32ull * 4096 * 3 * 4);
  short* h0       = (short*)alloc(32ull * 4096 * 64 * 2);
  short* hb       = (short*)alloc(32ull * 4096 * 64 * 2);
  short* fb       = (short*)alloc(32ull * 4096 * 64 * 2);
  int*   fps1     = (int*)alloc(32ull * 512 * 4);
  float* xyzc1    = (float*)alloc(32ull * 512 * 3 * 4);
  int*   knn1     = (int*)alloc(32ull * 512 * 32 * 4);
  short* f1       = (short*)alloc(32ull * 512 * 128 * 2);
  int*   fps2     = (int*)alloc(32ull * 256 * 4);
  int*   knn2     = (int*)alloc(32ull * 256 * 32 * 4);
  float* dming    = (float*)alloc(32ull * 4096 * 4);     // fps1 segment state
  int*   farg     = (int*)alloc(32 * 4);
  float* dming2   = (float*)alloc(32ull * 512 * 4);      // fps2 segment state
  int*   farg2    = (int*)alloc(32 * 4);
  short* hbuf     = (short*)alloc(134217728ull);          // shared SG1/SG2 h buffer
  float* mm1max   = (float*)alloc(16384ull * 128 * 4);    // SG1 per-center max/min
  float* mm1min   = (float*)alloc(16384ull * 128 * 4);
  float* mm2max   = (float*)alloc(8192ull * 256 * 4);     // SG2 per-center max/min
  float* mm2min   = (float*)alloc(8192ull * 256 * 4);
  float* partials = (float*)alloc(2ull * 256 * 8192 * 4); // 16 MB (NB up to 8192)
  float* scA  = (float*)alloc(64 * 4);  float* shA  = (float*)alloc(64 * 4);
  float* scBc = (float*)alloc(64 * 4);  float* shBc = (float*)alloc(64 * 4);
  float* sc1a = (float*)alloc(128 * 4); float* sh1a = (float*)alloc(128 * 4);
  float* sc1b = (float*)alloc(128 * 4); float* sh1b = (float*)alloc(128 * 4);
  float* sc2a = (float*)alloc(256 * 4); float* sh2a = (float*)alloc(256 * 4);
  float* sc2b = (float*)alloc(256 * 4); float* sh2b = (float*)alloc(256 * 4);
  short* w2b   = (short*)alloc(4096 * 2);
  short* s1w2b = (short*)alloc(16384 * 2);
  short* s2w2b = (short*)alloc(65536 * 2);
  short* W1pp  = (short*)alloc(16384 * 2);
  short* W2pp  = (short*)alloc(65536 * 2);

  prep_kernel<<<656, 256, 0, stream>>>(w2, s1w2, s2w2, s1w1, s2w1, w2b, s1w2b, s2w2b, W1pp, W2pp);
  stageA_kernel<<<512, 256, 0, stream>>>(x, w1, xyz, h0);

  // fps1 in 4x128-iter segments; companions: MLP chain + knn1 chunks of the
  // centers emitted by PREVIOUS segments (knn[s] only needs fps1[s]).
  fps_stats_seg<4096, 256><<<288, 256, 49216, stream>>>(
      32, xyz, fps1, xyzc1, 512, 0, 128, dming, farg, h0, partials, 131072, 256);
  fps_r2_knn_seg<4096, 256, 4096, 512><<<4192, 256, 49216, stream>>>(
      32, 64, xyz, fps1, xyzc1, 512, 128, 256, dming, farg,
      partials, g1, b1, scA, shA, 256, 64, 1.f / 131072.f,
      xyz, fps1, knn1, 0);
  fps_gemm_knn_seg<4096, 256, 64, 64, true, 0, 4096, 512><<<5152, 256, 49216, stream>>>(
      32, 1024, xyz, fps1, xyzc1, 512, 256, 384, dming, farg,
      h0, w2b, scA, shA, hb, partials,
      xyz, fps1, knn1, 128);
  fps_r2_knn_seg<4096, 256, 4096, 512><<<4192, 256, 49216, stream>>>(
      32, 64, xyz, fps1, xyzc1, 512, 384, 512, dming, farg,
      partials, g2, b2, scBc, shBc, 1024, 64, 1.f / 131072.f,
      xyz, fps1, knn1, 256);

  // launch5: fps2 segA [0,86) || knn1 tail [384,512) || BN apply -> fb
  fps2_knn_apply_kernel<512, 4096, 512><<<8224, 256, 0, stream>>>(
      32, xyzc1, fps2, 256, 0, 86, dming2, farg2,
      4096, xyz, fps1, knn1, 384, hb, fb, scBc, shBc);

  // launch6: fps2 segB [86,171) || SG1 gemm1 (gather, swizzle)
  mega1_kernel<512, 128, 128, 4096, 512><<<4128, 256, 35840, stream>>>(
      32, xyzc1, fps2, 256, 86, 171, dming2, farg2,
      fb, knn1, fps1, W1pp, hbuf, partials);
  reduce2_kernel<<<128, 256, 0, stream>>>(partials, s1g1, s1b1, sc1a, sh1a, 4096, 128, 1.f / 524288.f);

  // launch7: fps2 segC [171,256) || SG1 gemm2 (in-place BNA, max/min -> mm1)
  fps2_gemm_kernel<512, 128, 128><<<4128, 256, 35840, stream>>>(
      32, xyzc1, fps2, 256, 171, 256, dming2, farg2,
      hbuf, s1w2b, sc1a, sh1a, mm1max, mm1min, partials);
  reduce2_kernel<<<128, 256, 0, stream>>>(partials, s1g2, s1b2, sc1b, sh1b, 4096, 128, 1.f / 524288.f);

  // knn2 (8192 blocks) || maxpool_f1 from mm1 (8192 blocks, 2 centers each)
  maxpool_knn_kernel<512, 256><<<16384, 256, 0, stream>>>(
      8192, xyzc1, fps2, knn2, mm1max, mm1min, sc1b, sh1b, f1);

  // SG2 gemms: small-tile (BR=32, KC=32) for 5 waves/SIMD occupancy
  gemm_kernel5<256, 256, true, false, 512, 256, 0><<<8192, 256, 22528, stream>>>(
      f1, knn2, fps2, W2pp, nullptr, nullptr, hbuf, nullptr, nullptr, partials);
  reduce2_kernel<<<256, 256, 0, stream>>>(partials, s2g1, s2b1, sc2a, sh2a, 8192, 256, 1.f / 262144.f);
  gemm_kernel5<256, 256, false, true, 1, 1, 1><<<8192, 256, 22528, stream>>>(
      hbuf, nullptr, nullptr, s2w2b, sc2a, sh2a, nullptr, mm2max, mm2min, partials);
  reduce2_kernel<<<256, 256, 0, stream>>>(partials, s2g2, s2b2, sc2b, sh2b, 8192, 256, 1.f / 262144.f);
  maxpool_out_kernel<<<8192, 256, 0, stream>>>(mm2max, mm2min, sc2b, sh2b, out);
}

// Round 23
// 856.671 us; speedup vs baseline: 1.0258x; 1.0258x over previous
//
#include <hip/hip_runtime.h>

// ---------- types & helpers ----------
typedef short short8 __attribute__((ext_vector_type(8)));
typedef _Float16 h8 __attribute__((ext_vector_type(8)));
typedef float f32x4 __attribute__((ext_vector_type(4)));

#define DEVI __device__ __forceinline__

DEVI float h2f(short s) { return (float)__builtin_bit_cast(_Float16, s); }
DEVI short f2h(float f) { return __builtin_bit_cast(short, (_Float16)f); }
DEVI f32x4 mfma16(short8 a, short8 b, f32x4 c) {
  return __builtin_amdgcn_mfma_f32_16x16x32_f16(
      __builtin_bit_cast(h8, a), __builtin_bit_cast(h8, b), c, 0, 0, 0);
}

// ---------- DPP 64-lane reductions (gfx9 pattern), result broadcast ----------
DEVI float wave_max_bcast(float v) {
  const int ID = 0xff800000;  // -inf
  int x = __builtin_bit_cast(int, v);
#define STEPM(ctrl)                                                     \
  {                                                                     \
    int t = __builtin_amdgcn_update_dpp(ID, x, ctrl, 0xf, 0xf, false);  \
    x = __builtin_bit_cast(int, fmaxf(__builtin_bit_cast(float, x),     \
                                      __builtin_bit_cast(float, t)));   \
  }
  STEPM(0x111) STEPM(0x112) STEPM(0x114) STEPM(0x118) STEPM(0x142) STEPM(0x143)
#undef STEPM
  return __builtin_bit_cast(float, __builtin_amdgcn_readlane(x, 63));
}
DEVI float wave_min_bcast_f(float v) {
  const int ID = 0x7f800000;  // +inf
  int x = __builtin_bit_cast(int, v);
#define STEPN(ctrl)                                                     \
  {                                                                     \
    int t = __builtin_amdgcn_update_dpp(ID, x, ctrl, 0xf, 0xf, false);  \
    x = __builtin_bit_cast(int, fminf(__builtin_bit_cast(float, x),     \
                                      __builtin_bit_cast(float, t)));   \
  }
  STEPN(0x111) STEPN(0x112) STEPN(0x114) STEPN(0x118) STEPN(0x142) STEPN(0x143)
#undef STEPN
  return __builtin_bit_cast(float, __builtin_amdgcn_readlane(x, 63));
}
DEVI unsigned wave_min_bcast_u(unsigned v) {
  const int ID = (int)0xffffffff;
  int x = (int)v;
#define STEPU(ctrl)                                                     \
  {                                                                     \
    int t = __builtin_amdgcn_update_dpp(ID, x, ctrl, 0xf, 0xf, false);  \
    x = (int)((unsigned)x < (unsigned)t ? (unsigned)x : (unsigned)t);   \
  }
  STEPU(0x111) STEPU(0x112) STEPU(0x114) STEPU(0x118) STEPU(0x142) STEPU(0x143)
#undef STEPU
  return (unsigned)__builtin_amdgcn_readlane(x, 63);
}
// inclusive add-scan across 64 lanes (gfx9 dpp scan pattern)
DEVI unsigned wave_iscan_add(unsigned v) {
  int x = (int)v, t;
  t = __builtin_amdgcn_update_dpp(0, x, 0x111, 0xf, 0xf, false); x += t;
  t = __builtin_amdgcn_update_dpp(0, x, 0x112, 0xf, 0xf, false); x += t;
  t = __builtin_amdgcn_update_dpp(0, x, 0x114, 0xf, 0xf, false); x += t;
  t = __builtin_amdgcn_update_dpp(0, x, 0x118, 0xf, 0xf, false); x += t;
  t = __builtin_amdgcn_update_dpp(0, x, 0x142, 0xa, 0xf, false); x += t;
  t = __builtin_amdgcn_update_dpp(0, x, 0x143, 0xc, 0xf, false); x += t;
  return (unsigned)x;
}

// ---------- weight prep: f16 casts + folded W'' = [w1a | w1b - w1a] ----------
__global__ __launch_bounds__(256) void prep_kernel(
    const float* __restrict__ w2, const float* __restrict__ s1w2,
    const float* __restrict__ s2w2, const float* __restrict__ s1w1,
    const float* __restrict__ s2w1, short* __restrict__ w2b,
    short* __restrict__ s1w2b, short* __restrict__ s2w2b,
    short* __restrict__ W1pp, short* __restrict__ W2pp) {
  int i = blockIdx.x * 256 + threadIdx.x;
  if (i < 4096) {
    w2b[i] = f2h(w2[i]);
  } else if (i < 20480) {
    int j = i - 4096; s1w2b[j] = f2h(s1w2[j]);
  } else if (i < 86016) {
    int j = i - 20480; s2w2b[j] = f2h(s2w2[j]);
  } else if (i < 102400) {
    int j = i - 86016; int c = j & 127;
    float v = s1w1[j]; if (c >= 64) v -= s1w1[j - 64];
    W1pp[j] = f2h(v);
  } else if (i < 167936) {
    int j = i - 102400; int c = j & 255;
    float v = s2w1[j]; if (c >= 128) v -= s2w1[j - 128];
    W2pp[j] = f2h(v);
  }
}

// ---------- stage A: xyz transpose + h0 = x @ w1^T (K=3, VALU fp32) ----------
__global__ __launch_bounds__(256) void stageA_kernel(
    const float* __restrict__ x, const float* __restrict__ w1,
    float* __restrict__ xyz, short* __restrict__ h0) {
  int i = blockIdx.x * 256 + threadIdx.x;  // b*4096 + n, < 131072
  int b = i >> 12, n = i & 4095;
  const float* xb = x + ((size_t)b * 3 << 12) + n;
  float x0 = xb[0], x1 = xb[4096], x2 = xb[8192];
  float* xp = xyz + (size_t)i * 3;
  xp[0] = x0; xp[1] = x1; xp[2] = x2;
  short* hp = h0 + ((size_t)i << 6);
#pragma unroll
  for (int o8 = 0; o8 < 8; ++o8) {
    short8 t;
#pragma unroll
    for (int j = 0; j < 8; ++j) {
      int o = o8 * 8 + j;
      float h = x0 * w1[o * 3] + x1 * w1[o * 3 + 1] + x2 * w1[o * 3 + 2];
      t[j] = f2h(h);
    }
    *reinterpret_cast<short8*>(hp + o8 * 8) = t;
  }
}

// ---------- companion bodies ----------

DEVI void stats64_body(int bid, int nb, int tid, const short* __restrict__ h,
                       float* __restrict__ partials, int M) {
  __shared__ float l0[256], l1[256];
  const int c = tid & 63, g = tid >> 6;
  float s0 = 0.f, s1 = 0.f;
  for (int m = bid * 4 + g; m < M; m += nb * 4) {
    float v = h2f(h[(size_t)m * 64 + c]);
    s0 += v; s1 += v * v;
  }
  l0[tid] = s0; l1[tid] = s1;
  __syncthreads();
  if (g == 0) {
    for (int w = 1; w < 4; ++w) { s0 += l0[c + w * 64]; s1 += l1[c + w * 64]; }
    partials[(size_t)c * nb + bid] = s0;
    partials[(size_t)(64 + c) * nb + bid] = s1;
  }
}

DEVI void reduce2_body(int c, int tid, const float* __restrict__ partials,
                       const float* __restrict__ gamma, const float* __restrict__ beta,
                       float* __restrict__ scale, float* __restrict__ shift,
                       int NB, int C, float invM) {
  __shared__ float l0[4], l1[4];
  const float* p0 = partials + (size_t)c * NB;
  const float* p1 = partials + (size_t)(C + c) * NB;
  float s0 = 0.f, s1 = 0.f;
  for (int i = tid; i < NB; i += 256) { s0 += p0[i]; s1 += p1[i]; }
#pragma unroll
  for (int off = 1; off < 64; off <<= 1) {
    s0 += __shfl_xor(s0, off);
    s1 += __shfl_xor(s1, off);
  }
  if ((tid & 63) == 0) { l0[tid >> 6] = s0; l1[tid >> 6] = s1; }
  __syncthreads();
  if (tid == 0) {
    s0 = l0[0] + l0[1] + l0[2] + l0[3];
    s1 = l1[0] + l1[1] + l1[2] + l1[3];
    float mean = s0 * invM;
    float var = fmaxf(s1 * invM - mean * mean, 0.f);
    float sc = gamma[c] / sqrtf(var + 1e-5f);
    scale[c] = sc;
    shift[c] = beta[c] - mean * sc;
  }
}

__global__ __launch_bounds__(256) void reduce2_kernel(
    const float* __restrict__ partials, const float* __restrict__ gamma,
    const float* __restrict__ beta, float* __restrict__ scale,
    float* __restrict__ shift, int NB, int C, float invM) {
  reduce2_body(blockIdx.x, threadIdx.x, partials, gamma, beta, scale, shift, NB, C, invM);
}

// BN+ReLU apply, 8 f16/thread (C=64 tensors)
DEVI void apply_body(int bid, int tid, const short* __restrict__ h,
                     short* __restrict__ f, const float* __restrict__ scale,
                     const float* __restrict__ shift) {
  size_t i = ((size_t)bid * 256 + tid) * 8;
  int c0 = (int)(i & 63);
  short8 v = *reinterpret_cast<const short8*>(h + i);
  short8 o;
#pragma unroll
  for (int j = 0; j < 8; ++j) {
    float y = h2f(v[j]) * scale[c0 + j] + shift[c0 + j];
    o[j] = f2h(fmaxf(y, 0.f));
  }
  *reinterpret_cast<short8*>(f + i) = o;
}

// ---------- FPS body, segmented; exact numpy semantics ----------
template <int NPTS, int T>
DEVI void fps_seg_body(char* smemraw, int bid, int tid, const float* __restrict__ xyz,
                       int* __restrict__ out, float* __restrict__ xyzc, int nsel,
                       int it0, int it1, float* __restrict__ dming,
                       int* __restrict__ farg) {
  __builtin_amdgcn_s_setprio(1);
  constexpr int PT = NPTS / T;
  constexpr int NW = T / 64;
  float* sx = (float*)smemraw;
  float* sy = sx + NPTS;
  float* sz = sy + NPTS;
  float* wv = sz + NPTS;                    // [2][NW]
  unsigned* wi = (unsigned*)(wv + 2 * NW);  // [2][NW]
  const int lane = tid & 63, wave = tid >> 6;
  const float* base = xyz + (size_t)bid * NPTS * 3;
  float px[PT], py[PT], pz[PT], dmin[PT];
#pragma unroll
  for (int j = 0; j < PT; ++j) {
    int n = j * T + tid;
    px[j] = base[n * 3]; py[j] = base[n * 3 + 1]; pz[j] = base[n * 3 + 2];
    sx[n] = px[j]; sy[n] = py[j]; sz[n] = pz[j];
  }
  int far;
  if (it0 == 0) {
#pragma unroll
    for (int j = 0; j < PT; ++j) dmin[j] = 1e10f;
    far = 0;
  } else {
#pragma unroll
    for (int j = 0; j < PT; ++j) dmin[j] = dming[(size_t)bid * NPTS + j * T + tid];
    far = farg[bid];
  }
  __syncthreads();
  float cx = sx[far], cy = sy[far], cz = sz[far];
  for (int it = it0; it < it1; ++it) {
    if (tid == 0) {
      out[bid * nsel + it] = far;
      if (xyzc) {
        float* xc = xyzc + ((size_t)bid * nsel + it) * 3;
        xc[0] = cx; xc[1] = cy; xc[2] = cz;
      }
    }
    float bv = -1.f;
#pragma unroll
    for (int j = 0; j < PT; ++j) {
      float dx = __fsub_rn(px[j], cx), dy = __fsub_rn(py[j], cy), dz = __fsub_rn(pz[j], cz);
      float d = __fadd_rn(__fadd_rn(__fmul_rn(dx, dx), __fmul_rn(dy, dy)), __fmul_rn(dz, dz));
      float dm = fminf(dmin[j], d);
      dmin[j] = dm;
      bv = fmaxf(bv, dm);
    }
    float wmv = wave_max_bcast(bv);
    unsigned ci = 0xffffffffu;  // rescan, descending j -> smallest index kept
#pragma unroll
    for (int j = PT - 1; j >= 0; --j)
      if (dmin[j] == wmv) ci = (unsigned)(j * T + tid);
    unsigned wmi = wave_min_bcast_u(ci);
    const int bsel = it & 1;
    if (lane == 0) { wv[bsel * NW + wave] = wmv; wi[bsel * NW + wave] = wmi; }
    __syncthreads();
    const int e = lane & (NW - 1);
    float v = wv[bsel * NW + e];
    unsigned si = wi[bsel * NW + e];
#define CMB(ctrl)                                                                        \
  {                                                                                      \
    float v2 = __builtin_bit_cast(                                                       \
        float, __builtin_amdgcn_update_dpp(0, __builtin_bit_cast(int, v), ctrl, 0xf, 0xf, true)); \
    unsigned i2 = (unsigned)__builtin_amdgcn_update_dpp(0, (int)si, ctrl, 0xf, 0xf, true);\
    bool bt = (v2 > v) || (v2 == v && i2 < si);                                          \
    v = bt ? v2 : v; si = bt ? i2 : si;                                                  \
  }
    if constexpr (NW >= 2) CMB(0x121)   // row_ror:1
    if constexpr (NW >= 4) CMB(0x122)   // row_ror:2
    if constexpr (NW >= 8) CMB(0x124)   // row_ror:4
#undef CMB
    far = (int)si;
    cx = sx[far]; cy = sy[far]; cz = sz[far];  // broadcast LDS read, once/iter
  }
  if (it1 < nsel) {
#pragma unroll
    for (int j = 0; j < PT; ++j) dming[(size_t)bid * NPTS + j * T + tid] = dmin[j];
    if (tid == 0) farg[bid] = far;
  }
}

// ---------- kNN: exact top-32 SET via 4096-bucket histogram ----------
#define KNN_SMEM_BYTES ((4096 + 256 + 4 + 256 + 256) * 4)
template <int NPTS, int S>
DEVI void knn_body(char* smemraw, int bs, int tid, const float* __restrict__ pts,
                   const int* __restrict__ fpsidx, int* __restrict__ knn) {
  constexpr int PT = NPTS / 256;
  unsigned* hist = (unsigned*)smemraw;
  unsigned* csums = hist + 4096;
  unsigned* meta = csums + 256;   // 0: below-counter, 1: B, 2: cb, 3: boundary-counter
  float* bval = (float*)(meta + 4);
  unsigned* bidx = (unsigned*)(bval + 256);
  const int lane = tid & 63, wave = tid >> 6;
  const int b = bs / S;
  const int cidx = fpsidx[bs];
  const float* cp = pts + ((size_t)b * NPTS + cidx) * 3;
  const float qx = cp[0], qy = cp[1], qz = cp[2];
  const float qq = __fadd_rn(__fadd_rn(__fmul_rn(qx, qx), __fmul_rn(qy, qy)), __fmul_rn(qz, qz));
  const float* base = pts + (size_t)b * NPTS * 3;
  float d[PT]; unsigned u[PT];
#pragma unroll
  for (int j = 0; j < PT; ++j) {
    int n = j * 256 + tid;
    float x = base[n * 3], y = base[n * 3 + 1], z = base[n * 3 + 2];
    float pp = __fadd_rn(__fadd_rn(__fmul_rn(x, x), __fmul_rn(y, y)), __fmul_rn(z, z));
    float dot = __fadd_rn(__fadd_rn(__fmul_rn(qx, x), __fmul_rn(qy, y)), __fmul_rn(qz, z));
    d[j] = __fsub_rn(__fadd_rn(qq, pp), __fmul_rn(2.f, dot));
    unsigned bits = __builtin_bit_cast(unsigned, d[j]);
    unsigned m = (unsigned)((int)bits >> 31);
    u[j] = bits ^ (m | 0x80000000u);
  }
  {
    uint4 z4 = {0u, 0u, 0u, 0u};
    uint4* hq = (uint4*)hist;
    for (int i = tid; i < 1024; i += 256) hq[i] = z4;
    if (tid == 0) { meta[0] = 0; meta[3] = 0; }
  }
  __syncthreads();
#pragma unroll
  for (int j = 0; j < PT; ++j) atomicAdd(&hist[u[j] >> 20], 1u);
  __syncthreads();
  {
    const uint4* hq = (const uint4*)(hist + tid * 16);
    unsigned cs = 0;
#pragma unroll
    for (int q = 0; q < 4; ++q) {
      uint4 v = hq[q];
      cs += v.x + v.y + v.z + v.w;
    }
    csums[tid] = cs;
  }
  __syncthreads();
  if (wave == 0) {
    const int t4 = lane * 4;
    unsigned c0 = csums[t4], c1 = csums[t4 + 1], c2 = csums[t4 + 2], c3 = csums[t4 + 3];
    unsigned lt = c0 + c1 + c2 + c3;
    unsigned incl = wave_iscan_add(lt);
    unsigned excl = incl - lt;
    unsigned long long blt = __ballot(incl >= 32u);
    int L = __ffsll((long long)blt) - 1;
    if (lane == L) {
      unsigned cum = excl;
      int bucket = -1;
      unsigned cc[4] = {c0, c1, c2, c3};
#pragma unroll
      for (int q = 0; q < 4; ++q) {
        if (bucket < 0 && cum + cc[q] >= 32u) {
          int bbase = (t4 + q) * 16;
          for (int h = 0; h < 16; ++h) {
            unsigned hv = hist[bbase + h];
            if (cum + hv >= 32u) { bucket = bbase + h; break; }
            cum += hv;
          }
        } else if (bucket < 0) {
          cum += cc[q];
        }
      }
      meta[1] = (unsigned)bucket;
      meta[2] = cum;
    }
  }
  __syncthreads();
  const unsigned B = meta[1];
  const unsigned cb = meta[2];
  int* kout = knn + (size_t)bs * 32;
#pragma unroll
  for (int j = 0; j < PT; ++j) {
    unsigned bk = u[j] >> 20;
    if (bk < B) {
      unsigned p = atomicAdd(&meta[0], 1u);
      kout[p] = j * 256 + tid;
    } else if (bk == B) {
      unsigned p = atomicAdd(&meta[3], 1u);
      if (p < 256u) { bval[p] = d[j]; bidx[p] = (unsigned)(j * 256 + tid); }
    }
  }
  __syncthreads();
  const int m = 32 - (int)cb;
  if (wave == 0 && m > 0) {
    unsigned nb = meta[3]; if (nb > 256u) nb = 256u;
    float v0 = (lane < (int)nb) ? bval[lane] : 3.4e38f;
    unsigned i0 = (lane < (int)nb) ? bidx[lane] : 0xffffffffu;
    float v1 = (lane + 64 < (int)nb) ? bval[lane + 64] : 3.4e38f;
    unsigned i1 = (lane + 64 < (int)nb) ? bidx[lane + 64] : 0xffffffffu;
    float v2 = (lane + 128 < (int)nb) ? bval[lane + 128] : 3.4e38f;
    unsigned i2 = (lane + 128 < (int)nb) ? bidx[lane + 128] : 0xffffffffu;
    float v3 = (lane + 192 < (int)nb) ? bval[lane + 192] : 3.4e38f;
    unsigned i3 = (lane + 192 < (int)nb) ? bidx[lane + 192] : 0xffffffffu;
    for (int k = 0; k < m; ++k) {
      float lv = v0; unsigned li = i0;
      if (v1 < lv || (v1 == lv && i1 < li)) { lv = v1; li = i1; }
      if (v2 < lv || (v2 == lv && i2 < li)) { lv = v2; li = i2; }
      if (v3 < lv || (v3 == lv && i3 < li)) { lv = v3; li = i3; }
      float wmv = wave_min_bcast_f(lv);
      unsigned ci = (lv == wmv) ? li : 0xffffffffu;
      unsigned wmi = wave_min_bcast_u(ci);
      if (lane == 0) kout[cb + k] = (int)wmi;
      if (i0 == wmi) { v0 = 3.4e38f; i0 = 0xffffffffu; }
      if (i1 == wmi) { v1 = 3.4e38f; i1 = 0xffffffffu; }
      if (i2 == wmi) { v2 = 3.4e38f; i2 = 0xffffffffu; }
      if (i3 == wmi) { v3 = 3.4e38f; i3 = 0xffffffffu; }
    }
  }
}

// ---------- MFMA GEMM with chunked W-staging + BN stat partials ----------
// EPI 0: store full h via LDS-transposed coalesced short8 stores.
// EPI 1: per-center (32-row) fp32 max/min epilogue (no h materialization);
//        exact because BN is affine: max relu(sc*h+sh) = relu(sc*(sc>=0?max:min)+sh).
// ALDS: stage the A-tile (gathered rows) into LDS per K-chunk with coalesced
//       loads + per-row offsets resolved once -> inner loop is pure LDS+MFMA.
template <int KD, int ND, bool GATHER, bool BNA, int NPTS, int S, int EPI, bool ALDS>
DEVI void gemm_body(char* smemraw, int bid, int tid, int gemmBlocks,
                    const short* A, const int* KNNp, const int* FPSp,
                    const short* __restrict__ W, const float* __restrict__ bnscale,
                    const float* __restrict__ bnshift, short* Hout,
                    float* __restrict__ mmax, float* __restrict__ mmin,
                    float* __restrict__ partials) {
  constexpr int C = KD / 2;
  constexpr int NT = (ND > 128) ? 8 : ND / 16;
  constexpr int BR = (ND > 128) ? 64 : 128;
  constexpr int KC = (ND >= 256) ? 64 : KD;       // staging chunk k-width
  constexpr int LOG2KC = (KC == 64) ? 6 : 7;
  constexpr int NCH = KD / KC;
  constexpr int KTC = KC / 32;
  constexpr int LROW = KC + 8;                    // +16B pad -> 2-way alias (free)
  constexpr int ATROW = KC + 8;                   // A-tile pad
  constexpr int TROW = ND + 8;                    // epilogue tile pad
  constexpr int LBB = ND * LROW * 2;
  constexpr int TBB = BR * TROW * 2;
  constexpr int LSOFF = (LBB > TBB) ? LBB : TBB;
  short* lb = (short*)smemraw;                    // [ND][LROW]; reused as tile
  float* lstats = (float*)(smemraw + LSOFF);
  short* at = (short*)(smemraw + LSOFF + 2 * ND * 4);        // ALDS: [BR][ATROW]
  int* aoff = (int*)(smemraw + LSOFF + 2 * ND * 4 + BR * ATROW * 2);  // [BR][2]
  const int wave = tid >> 6, lane = tid & 63;
  const int rowOff = (ND > 128) ? (wave >> 1) * 32 : wave * 32;
  const int colOff = (ND > 128) ? (wave & 1) * 128 : 0;
  const int mBase = bid * BR + rowOff;
  for (int i = tid; i < 2 * ND; i += 256) lstats[i] = 0.f;

  const short* aptr[2][2];
  if constexpr (ALDS) {
    // per-row A element-offsets, gather resolved ONCE (not per k-step)
    if (tid < BR) {
      int m = bid * BR + tid;
      if constexpr (GATHER) {
        int idx = KNNp[m];
        int bb = m / (S * 32);
        int s = (m - bb * (S * 32)) >> 5;
        int fidx = FPSp[bb * S + s];
        aoff[tid * 2] = (bb * NPTS + idx) * C;
        aoff[tid * 2 + 1] = (bb * NPTS + fidx) * C;
      } else {
        aoff[tid * 2] = m * KD;
        aoff[tid * 2 + 1] = m * KD + C;
      }
    }
  } else {
#pragma unroll
    for (int rg = 0; rg < 2; ++rg) {
      int m = mBase + rg * 16 + (lane & 15);
      if constexpr (GATHER) {
        int idx = KNNp[m];
        int bb = m / (S * 32);
        int s = (m - bb * (S * 32)) >> 5;
        int fidx = FPSp[bb * S + s];
        aptr[rg][0] = A + ((size_t)bb * NPTS + idx) * C;
        aptr[rg][1] = A + ((size_t)bb * NPTS + fidx) * C;
      } else {
        aptr[rg][0] = A + (size_t)m * KD;
        aptr[rg][1] = A + (size_t)m * KD + C;
      }
    }
  }
  const int koLane = (lane >> 4) * 8;
  f32x4 acc[2][NT];
#pragma unroll
  for (int rg = 0; rg < 2; ++rg)
#pragma unroll
    for (int nt = 0; nt < NT; ++nt) acc[rg][nt] = (f32x4){0.f, 0.f, 0.f, 0.f};

#pragma unroll
  for (int ch = 0; ch < NCH; ++ch) {
    __syncthreads();
    constexpr int SIT = (ND * KC) / 2048;
#pragma unroll
    for (int i = 0; i < SIT; ++i) {
      int e = i * 2048 + tid * 8;
      int n = e >> LOG2KC, kk = e & (KC - 1);
      short8 v = *reinterpret_cast<const short8*>(W + (size_t)n * KD + ch * KC + kk);
      *reinterpret_cast<short8*>(&lb[n * LROW + kk]) = v;
    }
    if constexpr (ALDS) {
      // stage A k-slice: KC<=C so the whole chunk lies in one half
      constexpr int SITA = (BR * KC) / 2048;
      const int halfc = (ch * KC >= C) ? 1 : 0;
      const int kbase = ch * KC - halfc * C;
#pragma unroll
      for (int i = 0; i < SITA; ++i) {
        int e = i * 2048 + tid * 8;
        int n = e >> LOG2KC, kk = e & (KC - 1);
        short8 v = *reinterpret_cast<const short8*>(A + aoff[n * 2 + halfc] + kbase + kk);
        *reinterpret_cast<short8*>(&at[n * ATROW + kk]) = v;
      }
    }
    __syncthreads();
#pragma unroll
    for (int ktc = 0; ktc < KTC; ++ktc) {
      const int kt = ch * KTC + ktc;
      const int half = (kt * 32 >= C) ? 1 : 0;
      const int ko = kt * 32 + koLane;
      const int koh = ko - half * C;
      short8 afrag[2];
#pragma unroll
      for (int rg = 0; rg < 2; ++rg) {
        short8 a;
        if constexpr (ALDS) {
          a = *reinterpret_cast<const short8*>(
              &at[(rowOff + rg * 16 + (lane & 15)) * ATROW + ktc * 32 + koLane]);
        } else {
          a = *reinterpret_cast<const short8*>(aptr[rg][half] + koh);
        }
        if constexpr (BNA) {
          const float* scp = bnscale + ko;
          const float* shp = bnshift + ko;
#pragma unroll
          for (int j = 0; j < 8; ++j) {
            float v = h2f(a[j]);
            v = fmaxf(v * scp[j] + shp[j], 0.f);
            a[j] = f2h(v);
          }
        }
        afrag[rg] = a;
      }
#pragma unroll
      for (int nt = 0; nt < NT; ++nt) {
        short8 bfr = *reinterpret_cast<const short8*>(
            &lb[(colOff + nt * 16 + (lane & 15)) * LROW + ktc * 32 + koLane]);
        acc[0][nt] = mfma16(afrag[0], bfr, acc[0][nt]);
        acc[1][nt] = mfma16(afrag[1], bfr, acc[1][nt]);
      }
    }
  }
  __syncthreads();  // compute done: lb free, all A-reads retired

  // per-channel sum / sumsq partials (pre-BN stats of this layer's output)
#pragma unroll
  for (int nt = 0; nt < NT; ++nt) {
    float s0 = 0.f, s1 = 0.f;
#pragma unroll
    for (int rg = 0; rg < 2; ++rg)
#pragma unroll
      for (int i = 0; i < 4; ++i) {
        float v = acc[rg][nt][i];
        s0 += v; s1 += v * v;
      }
    s0 += __shfl_xor(s0, 16); s0 += __shfl_xor(s0, 32);
    s1 += __shfl_xor(s1, 16); s1 += __shfl_xor(s1, 32);
    if (lane < 16) {
      atomicAdd(&lstats[colOff + nt * 16 + lane], s0);
      atomicAdd(&lstats[ND + colOff + nt * 16 + lane], s1);
    }
  }

  if constexpr (EPI == 0) {
    // stage tile in LDS, then coalesced short8 stores
#pragma unroll
    for (int rg = 0; rg < 2; ++rg)
#pragma unroll
      for (int nt = 0; nt < NT; ++nt)
#pragma unroll
        for (int i = 0; i < 4; ++i) {
          int r = rowOff + rg * 16 + (lane >> 4) * 4 + i;
          int n = colOff + nt * 16 + (lane & 15);
          lb[r * TROW + n] = f2h(acc[rg][nt][i]);
        }
    __syncthreads();
    constexpr int TPR = ND / 8;       // threads per row
    constexpr int RPI = 256 / TPR;    // rows per iteration
    const int r0 = tid / TPR, c0 = (tid % TPR) * 8;
#pragma unroll
    for (int it = 0; it < BR / RPI; ++it) {
      int r = it * RPI + r0;
      short8 v = *reinterpret_cast<const short8*>(&lb[r * TROW + c0]);
      *reinterpret_cast<short8*>(&Hout[(size_t)(bid * BR + r) * ND + c0]) = v;
    }
  } else {
    // per-center max/min: each wave's rows cover its center's 32 rows jointly
    const int center = (bid * BR + rowOff) >> 5;
#pragma unroll
    for (int nt = 0; nt < NT; ++nt) {
      float mx = -3.4e38f, mn = 3.4e38f;
#pragma unroll
      for (int rg = 0; rg < 2; ++rg)
#pragma unroll
        for (int i = 0; i < 4; ++i) {
          float v = acc[rg][nt][i];
          mx = fmaxf(mx, v); mn = fminf(mn, v);
        }
      mx = fmaxf(mx, __shfl_xor(mx, 16)); mx = fmaxf(mx, __shfl_xor(mx, 32));
      mn = fminf(mn, __shfl_xor(mn, 16)); mn = fminf(mn, __shfl_xor(mn, 32));
      if (lane < 16) {
        mmax[(size_t)center * ND + colOff + nt * 16 + lane] = mx;
        mmin[(size_t)center * ND + colOff + nt * 16 + lane] = mn;
      }
    }
    __syncthreads();
  }
  for (int i = tid; i < 2 * ND; i += 256)
    partials[(size_t)i * gemmBlocks + bid] = lstats[i];
}

// ---------- fused wrappers ----------
// knn chunk mapping: 128 centers/chunk per batch; kb -> bs = (kb>>7)*S + s0 + (kb&127)

template <int FN, int FT>
__global__ __launch_bounds__(256, 1) void fps_stats_seg(
    int fpsBlocks, const float* fxyz, int* fout, float* fxyzc, int fnsel,
    int it0, int it1, float* dming, int* farg,
    const short* sh, float* sp, int sM, int snb) {
  extern __shared__ char smem[];
  if ((int)blockIdx.x < fpsBlocks)
    fps_seg_body<FN, FT>(smem, blockIdx.x, threadIdx.x, fxyz, fout, fxyzc, fnsel,
                         it0, it1, dming, farg);
  else
    stats64_body(blockIdx.x - fpsBlocks, snb, threadIdx.x, sh, sp, sM);
}

template <int FN, int FT, int KNPTS, int KS>
__global__ __launch_bounds__(256, 1) void fps_r2_knn_seg(
    int fpsBlocks, int compBlocks, const float* fxyz, int* fout, float* fxyzc,
    int fnsel, int it0, int it1, float* dming, int* farg,
    const float* partials, const float* gamma, const float* beta,
    float* scale, float* shift, int NB, int C, float invM,
    const float* kpts, const int* kfps, int* kout, int ks0) {
  extern __shared__ char smem[];
  const int bx = (int)blockIdx.x;
  if (bx < fpsBlocks) {
    fps_seg_body<FN, FT>(smem, bx, threadIdx.x, fxyz, fout, fxyzc, fnsel,
                         it0, it1, dming, farg);
  } else if (bx < fpsBlocks + compBlocks) {
    reduce2_body(bx - fpsBlocks, threadIdx.x, partials, gamma, beta, scale,
                 shift, NB, C, invM);
  } else {
    int kb = bx - fpsBlocks - compBlocks;
    int bs = (kb >> 7) * KS + ks0 + (kb & 127);
    knn_body<KNPTS, KS>(smem, bs, threadIdx.x, kpts, kfps, kout);
  }
}

template <int FN, int FT, int KD, int ND, bool BNA, int EPI, int KNPTS, int KS>
__global__ __launch_bounds__(256, 1) void fps_gemm_knn_seg(
    int fpsBlocks, int compBlocks, const float* fxyz, int* fout, float* fxyzc,
    int fnsel, int it0, int it1, float* dming, int* farg,
    const short* A, const short* W, const float* bnscale, const float* bnshift,
    short* Hout, float* partials,
    const float* kpts, const int* kfps, int* kout, int ks0) {
  extern __shared__ char smem[];
  const int bx = (int)blockIdx.x;
  if (bx < fpsBlocks) {
    fps_seg_body<FN, FT>(smem, bx, threadIdx.x, fxyz, fout, fxyzc, fnsel,
                         it0, it1, dming, farg);
  } else if (bx < fpsBlocks + compBlocks) {
    gemm_body<KD, ND, false, BNA, 1, 1, EPI, false>(smem, bx - fpsBlocks, threadIdx.x,
                                                    compBlocks, A, nullptr, nullptr,
                                                    W, bnscale, bnshift, Hout, nullptr,
                                                    nullptr, partials);
  } else {
    int kb = bx - fpsBlocks - compBlocks;
    int bs = (kb >> 7) * KS + ks0 + (kb & 127);
    knn_body<KNPTS, KS>(smem, bs, threadIdx.x, kpts, kfps, kout);
  }
}

// launch5: fps2 segA || last knn1 chunk || BN apply; full occupancy
template <int F2N, int NPTS, int S>
__global__ __launch_bounds__(256, 4) void fps2_knn_apply_kernel(
    int f2Blocks, const float* f2xyz, int* f2out, int f2nsel, int it0, int it1,
    float* dming2, int* farg2,
    int knnBlocks, const float* kpts, const int* kfps, int* kout, int ks0,
    const short* ah, short* af, const float* ascale, const float* ashift) {
  __shared__ __align__(16) char smem[KNN_SMEM_BYTES];
  const int bx = (int)blockIdx.x;
  if (bx < f2Blocks) {
    fps_seg_body<F2N, 256>(smem, bx, threadIdx.x, f2xyz, f2out, nullptr, f2nsel,
                           it0, it1, dming2, farg2);
  } else if (bx < f2Blocks + knnBlocks) {
    int kb = bx - f2Blocks;
    int bs = (kb >> 7) * S + ks0 + (kb & 127);
    knn_body<NPTS, S>(smem, bs, threadIdx.x, kpts, kfps, kout);
  } else {
    apply_body(bx - f2Blocks - knnBlocks, threadIdx.x, ah, af, ascale, ashift);
  }
}

// launch6: fps2 segB || SG1 gather gemm (XCD swizzle)
template <int F2N, int KD, int ND, int NPTS, int S>
__global__ __launch_bounds__(256, 4) void mega1_kernel(
    int f2Blocks, const float* f2xyz, int* f2out, int f2nsel, int it0, int it1,
    float* dming2, int* farg2,
    const short* A, const int* KNNp, const int* FPSp, const short* W,
    short* Hout, float* partials) {
  extern __shared__ char smem[];
  const int bx = (int)blockIdx.x;
  if (bx < f2Blocks) {
    fps_seg_body<F2N, 256>(smem, bx, threadIdx.x, f2xyz, f2out, nullptr, f2nsel,
                           it0, it1, dming2, farg2);
  } else {
    int gb = bx - f2Blocks;
    const int gB = (int)gridDim.x - f2Blocks;
    const int q = gB >> 3;
    gb = (gb & 7) * q + (gb >> 3);
    gemm_body<KD, ND, true, false, NPTS, S, 0, false>(smem, gb, threadIdx.x, gB, A,
                                                      KNNp, FPSp, W, nullptr, nullptr,
                                                      Hout, nullptr, nullptr, partials);
  }
}

// launch7: fps2 segC || SG1 gemm2 (in-place BNA, max/min epilogue)
template <int F2N, int KD, int ND>
__global__ __launch_bounds__(256, 4) void fps2_gemm_kernel(
    int f2Blocks, const float* f2xyz, int* f2out, int f2nsel, int it0, int it1,
    float* dming2, int* farg2,
    const short* A, const short* W, const float* bnscale, const float* bnshift,
    float* mmax, float* mmin, float* partials) {
  extern __shared__ char smem[];
  const int bx = (int)blockIdx.x;
  if (bx < f2Blocks) {
    fps_seg_body<F2N, 256>(smem, bx, threadIdx.x, f2xyz, f2out, nullptr, f2nsel,
                           it0, it1, dming2, farg2);
  } else {
    gemm_body<KD, ND, false, true, 1, 1, 1, false>(smem, bx - f2Blocks, threadIdx.x,
                                                   (int)gridDim.x - f2Blocks, A,
                                                   nullptr, nullptr, W, bnscale,
                                                   bnshift, nullptr, mmax, mmin,
                                                   partials);
  }
}

// standalone gemm; GATHER path gets bijective XCD swizzle (gridDim % 8 == 0)
template <int KD, int ND, bool GATHER, bool BNA, int NPTS, int S, int EPI, bool ALDS>
__global__ __launch_bounds__(256, 4) void gemm_kernel(
    const short* A, const int* KNNp, const int* FPSp, const short* W,
    const float* bnscale, const float* bnshift, short* Hout,
    float* mmax, float* mmin, float* partials) {
  extern __shared__ char smem[];
  int bid = (int)blockIdx.x;
  if constexpr (GATHER) {
    const int q = (int)gridDim.x >> 3;
    bid = (bid & 7) * q + (bid >> 3);
  }
  gemm_body<KD, ND, GATHER, BNA, NPTS, S, EPI, ALDS>(smem, bid, threadIdx.x,
                                                     gridDim.x, A, KNNp, FPSp, W,
                                                     bnscale, bnshift, Hout, mmax,
                                                     mmin, partials);
}

// knn2 blocks first, then maxpool-f1 blocks (from mm1 max/min; 2 centers/block)
template <int NPTS, int S>
__global__ __launch_bounds__(256, 4) void maxpool_knn_kernel(
    int knnBlocks, const float* pts, const int* fpsidx, int* knn,
    const float* mmax, const float* mmin, const float* scale, const float* shift,
    short* f1) {
  __shared__ __align__(16) char smem[KNN_SMEM_BYTES];
  if ((int)blockIdx.x < knnBlocks) {
    knn_body<NPTS, S>(smem, blockIdx.x, threadIdx.x, pts, fpsidx, knn);
  } else {
    const int ctr = (blockIdx.x - knnBlocks) * 2 + (threadIdx.x >> 7);
    const int c = threadIdx.x & 127;
    const float sc = scale[c], sh = shift[c];
    float y = (sc >= 0.f) ? mmax[(size_t)ctr * 128 + c] : mmin[(size_t)ctr * 128 + c];
    f1[(size_t)ctr * 128 + c] = f2h(fmaxf(sc * y + sh, 0.f));
  }
}

// ---------- final: BN+ReLU on per-center max/min, transposed fp32 out ----------
__global__ __launch_bounds__(256) void maxpool_out_kernel(
    const float* __restrict__ mmax, const float* __restrict__ mmin,
    const float* __restrict__ scale, const float* __restrict__ shift,
    float* __restrict__ out) {
  const int bs = blockIdx.x, c = threadIdx.x;
  const int b = bs >> 8, s = bs & 255;
  const float sc = scale[c], sh = shift[c];
  float y = (sc >= 0.f) ? mmax[(size_t)bs * 256 + c] : mmin[(size_t)bs * 256 + c];
  out[((size_t)b << 16) + ((size_t)c << 8) + s] = fmaxf(sc * y + sh, 0.f);
}

// ---------- launch ----------
extern "C" void kernel_launch(void* const* d_in, const int* in_sizes, int n_in,
                              void* d_out, int out_size, void* d_ws, size_t ws_size,
                              hipStream_t stream) {
  (void)in_sizes; (void)n_in; (void)out_size; (void)ws_size;
  const float* x    = (const float*)d_in[0];
  const float* w1   = (const float*)d_in[1];
  const float* g1   = (const float*)d_in[2];
  const float* b1   = (const float*)d_in[3];
  const float* w2   = (const float*)d_in[4];
  const float* g2   = (const float*)d_in[5];
  const float* b2   = (const float*)d_in[6];
  const float* s1w1 = (const float*)d_in[7];
  const float* s1g1 = (const float*)d_in[8];
  const float* s1b1 = (const float*)d_in[9];
  const float* s1w2 = (const float*)d_in[10];
  const float* s1g2 = (const float*)d_in[11];
  const float* s1b2 = (const float*)d_in[12];
  const float* s2w1 = (const float*)d_in[13];
  const float* s2g1 = (const float*)d_in[14];
  const float* s2b1 = (const float*)d_in[15];
  const float* s2w2 = (const float*)d_in[16];
  const float* s2g2 = (const float*)d_in[17];
  const float* s2b2 = (const float*)d_in[18];
  float* out = (float*)d_out;

  char* ws = (char*)d_ws;
  size_t off = 0;
  auto alloc = [&](size_t bytes) -> char* {
    size_t p = (off + 255) & ~(size_t)255;
    off = p + bytes;
    return ws + p;
  };

  float* xyz      = (float*)alloc(32ull * 4096 * 3 * 4);
  short* h0       = (short*)alloc(32ull * 4096 * 64 * 2);
  short* hb       = (short*)alloc(32ull * 4096 * 64 * 2);
  short* fb       = (short*)alloc(32ull * 4096 * 64 * 2);
  int*   fps1     = (int*)alloc(32ull * 512 * 4);
  float* xyzc1    = (float*)alloc(32ull * 512 * 3 * 4);
  int*   knn1     = (int*)alloc(32ull * 512 * 32 * 4);
  short* f1       = (short*)alloc(32ull * 512 * 128 * 2);
  int*   fps2     = (int*)alloc(32ull * 256 * 4);
  int*   knn2     = (int*)alloc(32ull * 256 * 32 * 4);
  float* dming    = (float*)alloc(32ull * 4096 * 4);     // fps1 segment state
  int*   farg     = (int*)alloc(32 * 4);
  float* dming2   = (float*)alloc(32ull * 512 * 4);      // fps2 segment state
  int*   farg2    = (int*)alloc(32 * 4);
  short* hbuf     = (short*)alloc(134217728ull);          // shared SG1/SG2 h buffer
  float* mm1max   = (float*)alloc(16384ull * 128 * 4);    // SG1 per-center max/min
  float* mm1min   = (float*)alloc(16384ull * 128 * 4);
  float* mm2max   = (float*)alloc(8192ull * 256 * 4);     // SG2 per-center max/min
  float* mm2min   = (float*)alloc(8192ull * 256 * 4);
  float* partials = (float*)alloc(2ull * 256 * 4096 * 4); // 8 MB
  float* scA  = (float*)alloc(64 * 4);  float* shA  = (float*)alloc(64 * 4);
  float* scBc = (float*)alloc(64 * 4);  float* shBc = (float*)alloc(64 * 4);
  float* sc1a = (float*)alloc(128 * 4); float* sh1a = (float*)alloc(128 * 4);
  float* sc1b = (float*)alloc(128 * 4); float* sh1b = (float*)alloc(128 * 4);
  float* sc2a = (float*)alloc(256 * 4); float* sh2a = (float*)alloc(256 * 4);
  float* sc2b = (float*)alloc(256 * 4); float* sh2b = (float*)alloc(256 * 4);
  short* w2b   = (short*)alloc(4096 * 2);
  short* s1w2b = (short*)alloc(16384 * 2);
  short* s2w2b = (short*)alloc(65536 * 2);
  short* W1pp  = (short*)alloc(16384 * 2);
  short* W2pp  = (short*)alloc(65536 * 2);

  prep_kernel<<<656, 256, 0, stream>>>(w2, s1w2, s2w2, s1w1, s2w1, w2b, s1w2b, s2w2b, W1pp, W2pp);
  stageA_kernel<<<512, 256, 0, stream>>>(x, w1, xyz, h0);

  // fps1 in 4x128-iter segments; companions: MLP chain + knn1 chunks of the
  // centers emitted by PREVIOUS segments (knn[s] only needs fps1[s]).
  fps_stats_seg<4096, 256><<<288, 256, 49216, stream>>>(
      32, xyz, fps1, xyzc1, 512, 0, 128, dming, farg, h0, partials, 131072, 256);
  fps_r2_knn_seg<4096, 256, 4096, 512><<<4192, 256, 49216, stream>>>(
      32, 64, xyz, fps1, xyzc1, 512, 128, 256, dming, farg,
      partials, g1, b1, scA, shA, 256, 64, 1.f / 131072.f,
      xyz, fps1, knn1, 0);
  fps_gemm_knn_seg<4096, 256, 64, 64, true, 0, 4096, 512><<<5152, 256, 49216, stream>>>(
      32, 1024, xyz, fps1, xyzc1, 512, 256, 384, dming, farg,
      h0, w2b, scA, shA, hb, partials,
      xyz, fps1, knn1, 128);
  fps_r2_knn_seg<4096, 256, 4096, 512><<<4192, 256, 49216, stream>>>(
      32, 64, xyz, fps1, xyzc1, 512, 384, 512, dming, farg,
      partials, g2, b2, scBc, shBc, 1024, 64, 1.f / 131072.f,
      xyz, fps1, knn1, 256);

  // launch5: fps2 segA [0,86) || knn1 tail [384,512) || BN apply -> fb
  fps2_knn_apply_kernel<512, 4096, 512><<<8224, 256, 0, stream>>>(
      32, xyzc1, fps2, 256, 0, 86, dming2, farg2,
      4096, xyz, fps1, knn1, 384, hb, fb, scBc, shBc);

  // launch6: fps2 segB [86,171) || SG1 gemm1 (gather, swizzle)
  mega1_kernel<512, 128, 128, 4096, 512><<<4128, 256, 35840, stream>>>(
      32, xyzc1, fps2, 256, 86, 171, dming2, farg2,
      fb, knn1, fps1, W1pp, hbuf, partials);
  reduce2_kernel<<<128, 256, 0, stream>>>(partials, s1g1, s1b1, sc1a, sh1a, 4096, 128, 1.f / 524288.f);

  // launch7: fps2 segC [171,256) || SG1 gemm2 (in-place BNA, max/min -> mm1)
  fps2_gemm_kernel<512, 128, 128><<<4128, 256, 35840, stream>>>(
      32, xyzc1, fps2, 256, 171, 256, dming2, farg2,
      hbuf, s1w2b, sc1a, sh1a, mm1max, mm1min, partials);
  reduce2_kernel<<<128, 256, 0, stream>>>(partials, s1g2, s1b2, sc1b, sh1b, 4096, 128, 1.f / 524288.f);

  // knn2 (8192 blocks) || maxpool_f1 from mm1 (8192 blocks, 2 centers each)
  maxpool_knn_kernel<512, 256><<<16384, 256, 0, stream>>>(
      8192, xyzc1, fps2, knn2, mm1max, mm1min, sc1b, sh1b, f1);

  // SG2 gemms with ALDS A-tile staging (LDS 48640 B -> 3 blocks/CU)
  gemm_kernel<256, 256, true, false, 512, 256, 0, true><<<4096, 256, 48640, stream>>>(
      f1, knn2, fps2, W2pp, nullptr, nullptr, hbuf, nullptr, nullptr, partials);
  reduce2_kernel<<<256, 256, 0, stream>>>(partials, s2g1, s2b1, sc2a, sh2a, 4096, 256, 1.f / 262144.f);
  gemm_kernel<256, 256, false, true, 1, 1, 1, true><<<4096, 256, 48640, stream>>>(
      hbuf, nullptr, nullptr, s2w2b, sc2a, sh2a, nullptr, mm2max, mm2min, partials);
  reduce2_kernel<<<256, 256, 0, stream>>>(partials, s2g2, s2b2, sc2b, sh2b, 4096, 256, 1.f / 262144.f);
  maxpool_out_kernel<<<8192, 256, 0, stream>>>(mm2max, mm2min, sc2b, sh2b, out);
}

// Round 24
// 795.001 us; speedup vs baseline: 1.1053x; 1.0776x over previous
//
#include <hip/hip_runtime.h>

// ---------- types & helpers ----------
typedef short short8 __attribute__((ext_vector_type(8)));
typedef _Float16 h8 __attribute__((ext_vector_type(8)));
typedef float f32x4 __attribute__((ext_vector_type(4)));

#define DEVI __device__ __forceinline__

DEVI float h2f(short s) { return (float)__builtin_bit_cast(_Float16, s); }
DEVI short f2h(float f) { return __builtin_bit_cast(short, (_Float16)f); }
DEVI f32x4 mfma16(short8 a, short8 b, f32x4 c) {
  return __builtin_amdgcn_mfma_f32_16x16x32_f16(
      __builtin_bit_cast(h8, a), __builtin_bit_cast(h8, b), c, 0, 0, 0);
}

// ---------- DPP 64-lane reductions (gfx9 pattern), result broadcast ----------
DEVI float wave_max_bcast(float v) {
  const int ID = 0xff800000;  // -inf
  int x = __builtin_bit_cast(int, v);
#define STEPM(ctrl)                                                     \
  {                                                                     \
    int t = __builtin_amdgcn_update_dpp(ID, x, ctrl, 0xf, 0xf, false);  \
    x = __builtin_bit_cast(int, fmaxf(__builtin_bit_cast(float, x),     \
                                      __builtin_bit_cast(float, t)));   \
  }
  STEPM(0x111) STEPM(0x112) STEPM(0x114) STEPM(0x118) STEPM(0x142) STEPM(0x143)
#undef STEPM
  return __builtin_bit_cast(float, __builtin_amdgcn_readlane(x, 63));
}
DEVI float wave_min_bcast_f(float v) {
  const int ID = 0x7f800000;  // +inf
  int x = __builtin_bit_cast(int, v);
#define STEPN(ctrl)                                                     \
  {                                                                     \
    int t = __builtin_amdgcn_update_dpp(ID, x, ctrl, 0xf, 0xf, false);  \
    x = __builtin_bit_cast(int, fminf(__builtin_bit_cast(float, x),     \
                                      __builtin_bit_cast(float, t)));   \
  }
  STEPN(0x111) STEPN(0x112) STEPN(0x114) STEPN(0x118) STEPN(0x142) STEPN(0x143)
#undef STEPN
  return __builtin_bit_cast(float, __builtin_amdgcn_readlane(x, 63));
}
DEVI unsigned wave_min_bcast_u(unsigned v) {
  const int ID = (int)0xffffffff;
  int x = (int)v;
#define STEPU(ctrl)                                                     \
  {                                                                     \
    int t = __builtin_amdgcn_update_dpp(ID, x, ctrl, 0xf, 0xf, false);  \
    x = (int)((unsigned)x < (unsigned)t ? (unsigned)x : (unsigned)t);   \
  }
  STEPU(0x111) STEPU(0x112) STEPU(0x114) STEPU(0x118) STEPU(0x142) STEPU(0x143)
#undef STEPU
  return (unsigned)__builtin_amdgcn_readlane(x, 63);
}
// inclusive add-scan across 64 lanes (gfx9 dpp scan pattern)
DEVI unsigned wave_iscan_add(unsigned v) {
  int x = (int)v, t;
  t = __builtin_amdgcn_update_dpp(0, x, 0x111, 0xf, 0xf, false); x += t;
  t = __builtin_amdgcn_update_dpp(0, x, 0x112, 0xf, 0xf, false); x += t;
  t = __builtin_amdgcn_update_dpp(0, x, 0x114, 0xf, 0xf, false); x += t;
  t = __builtin_amdgcn_update_dpp(0, x, 0x118, 0xf, 0xf, false); x += t;
  t = __builtin_amdgcn_update_dpp(0, x, 0x142, 0xa, 0xf, false); x += t;
  t = __builtin_amdgcn_update_dpp(0, x, 0x143, 0xc, 0xf, false); x += t;
  return (unsigned)x;
}

// ---------- weight prep: f16 casts + folded W'' = [w1a | w1b - w1a] ----------
__global__ __launch_bounds__(256) void prep_kernel(
    const float* __restrict__ w2, const float* __restrict__ s1w2,
    const float* __restrict__ s2w2, const float* __restrict__ s1w1,
    const float* __restrict__ s2w1, short* __restrict__ w2b,
    short* __restrict__ s1w2b, short* __restrict__ s2w2b,
    short* __restrict__ W1pp, short* __restrict__ W2pp) {
  int i = blockIdx.x * 256 + threadIdx.x;
  if (i < 4096) {
    w2b[i] = f2h(w2[i]);
  } else if (i < 20480) {
    int j = i - 4096; s1w2b[j] = f2h(s1w2[j]);
  } else if (i < 86016) {
    int j = i - 20480; s2w2b[j] = f2h(s2w2[j]);
  } else if (i < 102400) {
    int j = i - 86016; int c = j & 127;
    float v = s1w1[j]; if (c >= 64) v -= s1w1[j - 64];
    W1pp[j] = f2h(v);
  } else if (i < 167936) {
    int j = i - 102400; int c = j & 255;
    float v = s2w1[j]; if (c >= 128) v -= s2w1[j - 128];
    W2pp[j] = f2h(v);
  }
}

// ---------- stage A: xyz transpose + h0 = x @ w1^T (K=3, VALU fp32) ----------
__global__ __launch_bounds__(256) void stageA_kernel(
    const float* __restrict__ x, const float* __restrict__ w1,
    float* __restrict__ xyz, short* __restrict__ h0) {
  int i = blockIdx.x * 256 + threadIdx.x;  // b*4096 + n, < 131072
  int b = i >> 12, n = i & 4095;
  const float* xb = x + ((size_t)b * 3 << 12) + n;
  float x0 = xb[0], x1 = xb[4096], x2 = xb[8192];
  float* xp = xyz + (size_t)i * 3;
  xp[0] = x0; xp[1] = x1; xp[2] = x2;
  short* hp = h0 + ((size_t)i << 6);
#pragma unroll
  for (int o8 = 0; o8 < 8; ++o8) {
    short8 t;
#pragma unroll
    for (int j = 0; j < 8; ++j) {
      int o = o8 * 8 + j;
      float h = x0 * w1[o * 3] + x1 * w1[o * 3 + 1] + x2 * w1[o * 3 + 2];
      t[j] = f2h(h);
    }
    *reinterpret_cast<short8*>(hp + o8 * 8) = t;
  }
}

// ---------- companion bodies ----------

DEVI void stats64_body(int bid, int nb, int tid, const short* __restrict__ h,
                       float* __restrict__ partials, int M) {
  __shared__ float l0[256], l1[256];
  const int c = tid & 63, g = tid >> 6;
  float s0 = 0.f, s1 = 0.f;
  for (int m = bid * 4 + g; m < M; m += nb * 4) {
    float v = h2f(h[(size_t)m * 64 + c]);
    s0 += v; s1 += v * v;
  }
  l0[tid] = s0; l1[tid] = s1;
  __syncthreads();
  if (g == 0) {
    for (int w = 1; w < 4; ++w) { s0 += l0[c + w * 64]; s1 += l1[c + w * 64]; }
    partials[(size_t)c * nb + bid] = s0;
    partials[(size_t)(64 + c) * nb + bid] = s1;
  }
}

DEVI void reduce2_body(int c, int tid, const float* __restrict__ partials,
                       const float* __restrict__ gamma, const float* __restrict__ beta,
                       float* __restrict__ scale, float* __restrict__ shift,
                       int NB, int C, float invM) {
  __shared__ float l0[4], l1[4];
  const float* p0 = partials + (size_t)c * NB;
  const float* p1 = partials + (size_t)(C + c) * NB;
  float s0 = 0.f, s1 = 0.f;
  for (int i = tid; i < NB; i += 256) { s0 += p0[i]; s1 += p1[i]; }
#pragma unroll
  for (int off = 1; off < 64; off <<= 1) {
    s0 += __shfl_xor(s0, off);
    s1 += __shfl_xor(s1, off);
  }
  if ((tid & 63) == 0) { l0[tid >> 6] = s0; l1[tid >> 6] = s1; }
  __syncthreads();
  if (tid == 0) {
    s0 = l0[0] + l0[1] + l0[2] + l0[3];
    s1 = l1[0] + l1[1] + l1[2] + l1[3];
    float mean = s0 * invM;
    float var = fmaxf(s1 * invM - mean * mean, 0.f);
    float sc = gamma[c] / sqrtf(var + 1e-5f);
    scale[c] = sc;
    shift[c] = beta[c] - mean * sc;
  }
}

__global__ __launch_bounds__(256) void reduce2_kernel(
    const float* __restrict__ partials, const float* __restrict__ gamma,
    const float* __restrict__ beta, float* __restrict__ scale,
    float* __restrict__ shift, int NB, int C, float invM) {
  reduce2_body(blockIdx.x, threadIdx.x, partials, gamma, beta, scale, shift, NB, C, invM);
}

// BN+ReLU apply, 8 f16/thread (C=64 tensors)
DEVI void apply_body(int bid, int tid, const short* __restrict__ h,
                     short* __restrict__ f, const float* __restrict__ scale,
                     const float* __restrict__ shift) {
  size_t i = ((size_t)bid * 256 + tid) * 8;
  int c0 = (int)(i & 63);
  short8 v = *reinterpret_cast<const short8*>(h + i);
  short8 o;
#pragma unroll
  for (int j = 0; j < 8; ++j) {
    float y = h2f(v[j]) * scale[c0 + j] + shift[c0 + j];
    o[j] = f2h(fmaxf(y, 0.f));
  }
  *reinterpret_cast<short8*>(f + i) = o;
}

// ---------- FPS body, segmented; exact numpy semantics ----------
template <int NPTS, int T>
DEVI void fps_seg_body(char* smemraw, int bid, int tid, const float* __restrict__ xyz,
                       int* __restrict__ out, float* __restrict__ xyzc, int nsel,
                       int it0, int it1, float* __restrict__ dming,
                       int* __restrict__ farg) {
  __builtin_amdgcn_s_setprio(1);
  constexpr int PT = NPTS / T;
  constexpr int NW = T / 64;
  float* sx = (float*)smemraw;
  float* sy = sx + NPTS;
  float* sz = sy + NPTS;
  float* wv = sz + NPTS;                    // [2][NW]
  unsigned* wi = (unsigned*)(wv + 2 * NW);  // [2][NW]
  const int lane = tid & 63, wave = tid >> 6;
  const float* base = xyz + (size_t)bid * NPTS * 3;
  float px[PT], py[PT], pz[PT], dmin[PT];
#pragma unroll
  for (int j = 0; j < PT; ++j) {
    int n = j * T + tid;
    px[j] = base[n * 3]; py[j] = base[n * 3 + 1]; pz[j] = base[n * 3 + 2];
    sx[n] = px[j]; sy[n] = py[j]; sz[n] = pz[j];
  }
  int far;
  if (it0 == 0) {
#pragma unroll
    for (int j = 0; j < PT; ++j) dmin[j] = 1e10f;
    far = 0;
  } else {
#pragma unroll
    for (int j = 0; j < PT; ++j) dmin[j] = dming[(size_t)bid * NPTS + j * T + tid];
    far = farg[bid];
  }
  __syncthreads();
  float cx = sx[far], cy = sy[far], cz = sz[far];
  for (int it = it0; it < it1; ++it) {
    if (tid == 0) {
      out[bid * nsel + it] = far;
      if (xyzc) {
        float* xc = xyzc + ((size_t)bid * nsel + it) * 3;
        xc[0] = cx; xc[1] = cy; xc[2] = cz;
      }
    }
    float bv = -1.f;
#pragma unroll
    for (int j = 0; j < PT; ++j) {
      float dx = __fsub_rn(px[j], cx), dy = __fsub_rn(py[j], cy), dz = __fsub_rn(pz[j], cz);
      float d = __fadd_rn(__fadd_rn(__fmul_rn(dx, dx), __fmul_rn(dy, dy)), __fmul_rn(dz, dz));
      float dm = fminf(dmin[j], d);
      dmin[j] = dm;
      bv = fmaxf(bv, dm);
    }
    float wmv = wave_max_bcast(bv);
    unsigned ci = 0xffffffffu;  // rescan, descending j -> smallest index kept
#pragma unroll
    for (int j = PT - 1; j >= 0; --j)
      if (dmin[j] == wmv) ci = (unsigned)(j * T + tid);
    unsigned wmi = wave_min_bcast_u(ci);
    const int bsel = it & 1;
    if (lane == 0) { wv[bsel * NW + wave] = wmv; wi[bsel * NW + wave] = wmi; }
    __syncthreads();
    const int e = lane & (NW - 1);
    float v = wv[bsel * NW + e];
    unsigned si = wi[bsel * NW + e];
#define CMB(ctrl)                                                                        \
  {                                                                                      \
    float v2 = __builtin_bit_cast(                                                       \
        float, __builtin_amdgcn_update_dpp(0, __builtin_bit_cast(int, v), ctrl, 0xf, 0xf, true)); \
    unsigned i2 = (unsigned)__builtin_amdgcn_update_dpp(0, (int)si, ctrl, 0xf, 0xf, true);\
    bool bt = (v2 > v) || (v2 == v && i2 < si);                                          \
    v = bt ? v2 : v; si = bt ? i2 : si;                                                  \
  }
    if constexpr (NW >= 2) CMB(0x121)   // row_ror:1
    if constexpr (NW >= 4) CMB(0x122)   // row_ror:2
    if constexpr (NW >= 8) CMB(0x124)   // row_ror:4
#undef CMB
    far = (int)si;
    cx = sx[far]; cy = sy[far]; cz = sz[far];  // broadcast LDS read, once/iter
  }
  if (it1 < nsel) {
#pragma unroll
    for (int j = 0; j < PT; ++j) dming[(size_t)bid * NPTS + j * T + tid] = dmin[j];
    if (tid == 0) farg[bid] = far;
  }
}

// ---------- kNN: exact top-32 SET via 4096-bucket histogram ----------
#define KNN_SMEM_BYTES ((4096 + 256 + 4 + 256 + 256) * 4)
template <int NPTS, int S>
DEVI void knn_body(char* smemraw, int bs, int tid, const float* __restrict__ pts,
                   const int* __restrict__ fpsidx, int* __restrict__ knn) {
  constexpr int PT = NPTS / 256;
  unsigned* hist = (unsigned*)smemraw;
  unsigned* csums = hist + 4096;
  unsigned* meta = csums + 256;   // 0: below-counter, 1: B, 2: cb, 3: boundary-counter
  float* bval = (float*)(meta + 4);
  unsigned* bidx = (unsigned*)(bval + 256);
  const int lane = tid & 63, wave = tid >> 6;
  const int b = bs / S;
  const int cidx = fpsidx[bs];
  const float* cp = pts + ((size_t)b * NPTS + cidx) * 3;
  const float qx = cp[0], qy = cp[1], qz = cp[2];
  const float qq = __fadd_rn(__fadd_rn(__fmul_rn(qx, qx), __fmul_rn(qy, qy)), __fmul_rn(qz, qz));
  const float* base = pts + (size_t)b * NPTS * 3;
  float d[PT]; unsigned u[PT];
#pragma unroll
  for (int j = 0; j < PT; ++j) {
    int n = j * 256 + tid;
    float x = base[n * 3], y = base[n * 3 + 1], z = base[n * 3 + 2];
    float pp = __fadd_rn(__fadd_rn(__fmul_rn(x, x), __fmul_rn(y, y)), __fmul_rn(z, z));
    float dot = __fadd_rn(__fadd_rn(__fmul_rn(qx, x), __fmul_rn(qy, y)), __fmul_rn(qz, z));
    d[j] = __fsub_rn(__fadd_rn(qq, pp), __fmul_rn(2.f, dot));
    unsigned bits = __builtin_bit_cast(unsigned, d[j]);
    unsigned m = (unsigned)((int)bits >> 31);
    u[j] = bits ^ (m | 0x80000000u);
  }
  {
    uint4 z4 = {0u, 0u, 0u, 0u};
    uint4* hq = (uint4*)hist;
    for (int i = tid; i < 1024; i += 256) hq[i] = z4;
    if (tid == 0) { meta[0] = 0; meta[3] = 0; }
  }
  __syncthreads();
#pragma unroll
  for (int j = 0; j < PT; ++j) atomicAdd(&hist[u[j] >> 20], 1u);
  __syncthreads();
  {
    const uint4* hq = (const uint4*)(hist + tid * 16);
    unsigned cs = 0;
#pragma unroll
    for (int q = 0; q < 4; ++q) {
      uint4 v = hq[q];
      cs += v.x + v.y + v.z + v.w;
    }
    csums[tid] = cs;
  }
  __syncthreads();
  if (wave == 0) {
    const int t4 = lane * 4;
    unsigned c0 = csums[t4], c1 = csums[t4 + 1], c2 = csums[t4 + 2], c3 = csums[t4 + 3];
    unsigned lt = c0 + c1 + c2 + c3;
    unsigned incl = wave_iscan_add(lt);
    unsigned excl = incl - lt;
    unsigned long long blt = __ballot(incl >= 32u);
    int L = __ffsll((long long)blt) - 1;
    if (lane == L) {
      unsigned cum = excl;
      int bucket = -1;
      unsigned cc[4] = {c0, c1, c2, c3};
#pragma unroll
      for (int q = 0; q < 4; ++q) {
        if (bucket < 0 && cum + cc[q] >= 32u) {
          int bbase = (t4 + q) * 16;
          for (int h = 0; h < 16; ++h) {
            unsigned hv = hist[bbase + h];
            if (cum + hv >= 32u) { bucket = bbase + h; break; }
            cum += hv;
          }
        } else if (bucket < 0) {
          cum += cc[q];
        }
      }
      meta[1] = (unsigned)bucket;
      meta[2] = cum;
    }
  }
  __syncthreads();
  const unsigned B = meta[1];
  const unsigned cb = meta[2];
  int* kout = knn + (size_t)bs * 32;
#pragma unroll
  for (int j = 0; j < PT; ++j) {
    unsigned bk = u[j] >> 20;
    if (bk < B) {
      unsigned p = atomicAdd(&meta[0], 1u);
      kout[p] = j * 256 + tid;
    } else if (bk == B) {
      unsigned p = atomicAdd(&meta[3], 1u);
      if (p < 256u) { bval[p] = d[j]; bidx[p] = (unsigned)(j * 256 + tid); }
    }
  }
  __syncthreads();
  const int m = 32 - (int)cb;
  if (wave == 0 && m > 0) {
    unsigned nb = meta[3]; if (nb > 256u) nb = 256u;
    float v0 = (lane < (int)nb) ? bval[lane] : 3.4e38f;
    unsigned i0 = (lane < (int)nb) ? bidx[lane] : 0xffffffffu;
    float v1 = (lane + 64 < (int)nb) ? bval[lane + 64] : 3.4e38f;
    unsigned i1 = (lane + 64 < (int)nb) ? bidx[lane + 64] : 0xffffffffu;
    float v2 = (lane + 128 < (int)nb) ? bval[lane + 128] : 3.4e38f;
    unsigned i2 = (lane + 128 < (int)nb) ? bidx[lane + 128] : 0xffffffffu;
    float v3 = (lane + 192 < (int)nb) ? bval[lane + 192] : 3.4e38f;
    unsigned i3 = (lane + 192 < (int)nb) ? bidx[lane + 192] : 0xffffffffu;
    for (int k = 0; k < m; ++k) {
      float lv = v0; unsigned li = i0;
      if (v1 < lv || (v1 == lv && i1 < li)) { lv = v1; li = i1; }
      if (v2 < lv || (v2 == lv && i2 < li)) { lv = v2; li = i2; }
      if (v3 < lv || (v3 == lv && i3 < li)) { lv = v3; li = i3; }
      float wmv = wave_min_bcast_f(lv);
      unsigned ci = (lv == wmv) ? li : 0xffffffffu;
      unsigned wmi = wave_min_bcast_u(ci);
      if (lane == 0) kout[cb + k] = (int)wmi;
      if (i0 == wmi) { v0 = 3.4e38f; i0 = 0xffffffffu; }
      if (i1 == wmi) { v1 = 3.4e38f; i1 = 0xffffffffu; }
      if (i2 == wmi) { v2 = 3.4e38f; i2 = 0xffffffffu; }
      if (i3 == wmi) { v3 = 3.4e38f; i3 = 0xffffffffu; }
    }
  }
}

// ---------- MFMA GEMM with chunked W-staging + BN stat partials ----------
// EPI 0: store full h via LDS-transposed coalesced short8 stores.
// EPI 1: per-center (32-row) fp32 max/min epilogue (no h materialization);
//        exact because BN is affine: max relu(sc*h+sh) = relu(sc*(sc>=0?max:min)+sh).
template <int KD, int ND, bool GATHER, bool BNA, int NPTS, int S, int EPI>
DEVI void gemm_body(char* smemraw, int bid, int tid, int gemmBlocks,
                    const short* A, const int* KNNp, const int* FPSp,
                    const short* __restrict__ W, const float* __restrict__ bnscale,
                    const float* __restrict__ bnshift, short* Hout,
                    float* __restrict__ mmax, float* __restrict__ mmin,
                    float* __restrict__ partials) {
  constexpr int C = KD / 2;
  constexpr int NT = (ND > 128) ? 8 : ND / 16;
  constexpr int BR = (ND > 128) ? 64 : 128;
  constexpr int KC = (ND >= 256) ? 64 : KD;       // staging chunk k-width
  constexpr int LOG2KC = (KC == 64) ? 6 : 7;
  constexpr int NCH = KD / KC;
  constexpr int KTC = KC / 32;
  constexpr int LROW = KC + 8;                    // +16B pad -> 2-way alias (free)
  constexpr int TROW = ND + 8;                    // epilogue tile pad
  constexpr int LBB = ND * LROW * 2;
  constexpr int TBB = BR * TROW * 2;
  constexpr int LSOFF = (LBB > TBB) ? LBB : TBB;
  short* lb = (short*)smemraw;                    // [ND][LROW]; reused as tile
  float* lstats = (float*)(smemraw + LSOFF);
  const int wave = tid >> 6, lane = tid & 63;
  const int rowOff = (ND > 128) ? (wave >> 1) * 32 : wave * 32;
  const int colOff = (ND > 128) ? (wave & 1) * 128 : 0;
  const int mBase = bid * BR + rowOff;
  for (int i = tid; i < 2 * ND; i += 256) lstats[i] = 0.f;

  const short* aptr[2][2];
#pragma unroll
  for (int rg = 0; rg < 2; ++rg) {
    int m = mBase + rg * 16 + (lane & 15);
    if constexpr (GATHER) {
      int idx = KNNp[m];
      int bb = m / (S * 32);
      int s = (m - bb * (S * 32)) >> 5;
      int fidx = FPSp[bb * S + s];
      aptr[rg][0] = A + ((size_t)bb * NPTS + idx) * C;
      aptr[rg][1] = A + ((size_t)bb * NPTS + fidx) * C;
    } else {
      aptr[rg][0] = A + (size_t)m * KD;
      aptr[rg][1] = A + (size_t)m * KD + C;
    }
  }
  const int koLane = (lane >> 4) * 8;
  f32x4 acc[2][NT];
#pragma unroll
  for (int rg = 0; rg < 2; ++rg)
#pragma unroll
    for (int nt = 0; nt < NT; ++nt) acc[rg][nt] = (f32x4){0.f, 0.f, 0.f, 0.f};

#pragma unroll
  for (int ch = 0; ch < NCH; ++ch) {
    __syncthreads();
    constexpr int SIT = (ND * KC) / 2048;
#pragma unroll
    for (int i = 0; i < SIT; ++i) {
      int e = i * 2048 + tid * 8;
      int n = e >> LOG2KC, kk = e & (KC - 1);
      short8 v = *reinterpret_cast<const short8*>(W + (size_t)n * KD + ch * KC + kk);
      *reinterpret_cast<short8*>(&lb[n * LROW + kk]) = v;
    }
    __syncthreads();
#pragma unroll
    for (int ktc = 0; ktc < KTC; ++ktc) {
      const int kt = ch * KTC + ktc;
      const int half = (kt * 32 >= C) ? 1 : 0;
      const int ko = kt * 32 + koLane;
      const int koh = ko - half * C;
      short8 afrag[2];
#pragma unroll
      for (int rg = 0; rg < 2; ++rg) {
        short8 a = *reinterpret_cast<const short8*>(aptr[rg][half] + koh);
        if constexpr (BNA) {
          const float* scp = bnscale + ko;
          const float* shp = bnshift + ko;
#pragma unroll
          for (int j = 0; j < 8; ++j) {
            float v = h2f(a[j]);
            v = fmaxf(v * scp[j] + shp[j], 0.f);
            a[j] = f2h(v);
          }
        }
        afrag[rg] = a;
      }
#pragma unroll
      for (int nt = 0; nt < NT; ++nt) {
        short8 bfr = *reinterpret_cast<const short8*>(
            &lb[(colOff + nt * 16 + (lane & 15)) * LROW + ktc * 32 + koLane]);
        acc[0][nt] = mfma16(afrag[0], bfr, acc[0][nt]);
        acc[1][nt] = mfma16(afrag[1], bfr, acc[1][nt]);
      }
    }
  }
  __syncthreads();  // compute done: lb free, all A-reads retired

  // per-channel sum / sumsq partials (pre-BN stats of this layer's output)
#pragma unroll
  for (int nt = 0; nt < NT; ++nt) {
    float s0 = 0.f, s1 = 0.f;
#pragma unroll
    for (int rg = 0; rg < 2; ++rg)
#pragma unroll
      for (int i = 0; i < 4; ++i) {
        float v = acc[rg][nt][i];
        s0 += v; s1 += v * v;
      }
    s0 += __shfl_xor(s0, 16); s0 += __shfl_xor(s0, 32);
    s1 += __shfl_xor(s1, 16); s1 += __shfl_xor(s1, 32);
    if (lane < 16) {
      atomicAdd(&lstats[colOff + nt * 16 + lane], s0);
      atomicAdd(&lstats[ND + colOff + nt * 16 + lane], s1);
    }
  }

  if constexpr (EPI == 0) {
    // stage tile in LDS, then coalesced short8 stores
#pragma unroll
    for (int rg = 0; rg < 2; ++rg)
#pragma unroll
      for (int nt = 0; nt < NT; ++nt)
#pragma unroll
        for (int i = 0; i < 4; ++i) {
          int r = rowOff + rg * 16 + (lane >> 4) * 4 + i;
          int n = colOff + nt * 16 + (lane & 15);
          lb[r * TROW + n] = f2h(acc[rg][nt][i]);
        }
    __syncthreads();
    constexpr int TPR = ND / 8;       // threads per row
    constexpr int RPI = 256 / TPR;    // rows per iteration
    const int r0 = tid / TPR, c0 = (tid % TPR) * 8;
#pragma unroll
    for (int it = 0; it < BR / RPI; ++it) {
      int r = it * RPI + r0;
      short8 v = *reinterpret_cast<const short8*>(&lb[r * TROW + c0]);
      *reinterpret_cast<short8*>(&Hout[(size_t)(bid * BR + r) * ND + c0]) = v;
    }
  } else {
    // per-center max/min: each wave's rows cover its center's 32 rows jointly
    const int center = (bid * BR + rowOff) >> 5;
#pragma unroll
    for (int nt = 0; nt < NT; ++nt) {
      float mx = -3.4e38f, mn = 3.4e38f;
#pragma unroll
      for (int rg = 0; rg < 2; ++rg)
#pragma unroll
        for (int i = 0; i < 4; ++i) {
          float v = acc[rg][nt][i];
          mx = fmaxf(mx, v); mn = fminf(mn, v);
        }
      mx = fmaxf(mx, __shfl_xor(mx, 16)); mx = fmaxf(mx, __shfl_xor(mx, 32));
      mn = fminf(mn, __shfl_xor(mn, 16)); mn = fminf(mn, __shfl_xor(mn, 32));
      if (lane < 16) {
        mmax[(size_t)center * ND + colOff + nt * 16 + lane] = mx;
        mmin[(size_t)center * ND + colOff + nt * 16 + lane] = mn;
      }
    }
    __syncthreads();
  }
  for (int i = tid; i < 2 * ND; i += 256)
    partials[(size_t)i * gemmBlocks + bid] = lstats[i];
}

// ---------- fused wrappers ----------
// knn chunk mapping: 128 centers/chunk per batch; kb -> bs = (kb>>7)*S + s0 + (kb&127)

template <int FN, int FT>
__global__ __launch_bounds__(256, 1) void fps_stats_seg(
    int fpsBlocks, const float* fxyz, int* fout, float* fxyzc, int fnsel,
    int it0, int it1, float* dming, int* farg,
    const short* sh, float* sp, int sM, int snb) {
  extern __shared__ char smem[];
  if ((int)blockIdx.x < fpsBlocks)
    fps_seg_body<FN, FT>(smem, blockIdx.x, threadIdx.x, fxyz, fout, fxyzc, fnsel,
                         it0, it1, dming, farg);
  else
    stats64_body(blockIdx.x - fpsBlocks, snb, threadIdx.x, sh, sp, sM);
}

template <int FN, int FT, int KNPTS, int KS>
__global__ __launch_bounds__(256, 1) void fps_r2_knn_seg(
    int fpsBlocks, int compBlocks, const float* fxyz, int* fout, float* fxyzc,
    int fnsel, int it0, int it1, float* dming, int* farg,
    const float* partials, const float* gamma, const float* beta,
    float* scale, float* shift, int NB, int C, float invM,
    const float* kpts, const int* kfps, int* kout, int ks0) {
  extern __shared__ char smem[];
  const int bx = (int)blockIdx.x;
  if (bx < fpsBlocks) {
    fps_seg_body<FN, FT>(smem, bx, threadIdx.x, fxyz, fout, fxyzc, fnsel,
                         it0, it1, dming, farg);
  } else if (bx < fpsBlocks + compBlocks) {
    reduce2_body(bx - fpsBlocks, threadIdx.x, partials, gamma, beta, scale,
                 shift, NB, C, invM);
  } else {
    int kb = bx - fpsBlocks - compBlocks;
    int bs = (kb >> 7) * KS + ks0 + (kb & 127);
    knn_body<KNPTS, KS>(smem, bs, threadIdx.x, kpts, kfps, kout);
  }
}

template <int FN, int FT, int KD, int ND, bool BNA, int EPI, int KNPTS, int KS>
__global__ __launch_bounds__(256, 1) void fps_gemm_knn_seg(
    int fpsBlocks, int compBlocks, const float* fxyz, int* fout, float* fxyzc,
    int fnsel, int it0, int it1, float* dming, int* farg,
    const short* A, const short* W, const float* bnscale, const float* bnshift,
    short* Hout, float* partials,
    const float* kpts, const int* kfps, int* kout, int ks0) {
  extern __shared__ char smem[];
  const int bx = (int)blockIdx.x;
  if (bx < fpsBlocks) {
    fps_seg_body<FN, FT>(smem, bx, threadIdx.x, fxyz, fout, fxyzc, fnsel,
                         it0, it1, dming, farg);
  } else if (bx < fpsBlocks + compBlocks) {
    gemm_body<KD, ND, false, BNA, 1, 1, EPI>(smem, bx - fpsBlocks, threadIdx.x,
                                             compBlocks, A, nullptr, nullptr,
                                             W, bnscale, bnshift, Hout, nullptr,
                                             nullptr, partials);
  } else {
    int kb = bx - fpsBlocks - compBlocks;
    int bs = (kb >> 7) * KS + ks0 + (kb & 127);
    knn_body<KNPTS, KS>(smem, bs, threadIdx.x, kpts, kfps, kout);
  }
}

// launch5: fps2 segA || last knn1 chunk || BN apply; full occupancy
template <int F2N, int NPTS, int S>
__global__ __launch_bounds__(256, 4) void fps2_knn_apply_kernel(
    int f2Blocks, const float* f2xyz, int* f2out, int f2nsel, int it0, int it1,
    float* dming2, int* farg2,
    int knnBlocks, const float* kpts, const int* kfps, int* kout, int ks0,
    const short* ah, short* af, const float* ascale, const float* ashift) {
  __shared__ __align__(16) char smem[KNN_SMEM_BYTES];
  const int bx = (int)blockIdx.x;
  if (bx < f2Blocks) {
    fps_seg_body<F2N, 256>(smem, bx, threadIdx.x, f2xyz, f2out, nullptr, f2nsel,
                           it0, it1, dming2, farg2);
  } else if (bx < f2Blocks + knnBlocks) {
    int kb = bx - f2Blocks;
    int bs = (kb >> 7) * S + ks0 + (kb & 127);
    knn_body<NPTS, S>(smem, bs, threadIdx.x, kpts, kfps, kout);
  } else {
    apply_body(bx - f2Blocks - knnBlocks, threadIdx.x, ah, af, ascale, ashift);
  }
}

// launch6: fps2 segB || SG1 gather gemm (XCD swizzle)
template <int F2N, int KD, int ND, int NPTS, int S>
__global__ __launch_bounds__(256, 4) void mega1_kernel(
    int f2Blocks, const float* f2xyz, int* f2out, int f2nsel, int it0, int it1,
    float* dming2, int* farg2,
    const short* A, const int* KNNp, const int* FPSp, const short* W,
    short* Hout, float* partials) {
  extern __shared__ char smem[];
  const int bx = (int)blockIdx.x;
  if (bx < f2Blocks) {
    fps_seg_body<F2N, 256>(smem, bx, threadIdx.x, f2xyz, f2out, nullptr, f2nsel,
                           it0, it1, dming2, farg2);
  } else {
    int gb = bx - f2Blocks;
    const int gB = (int)gridDim.x - f2Blocks;
    const int q = gB >> 3;
    gb = (gb & 7) * q + (gb >> 3);
    gemm_body<KD, ND, true, false, NPTS, S, 0>(smem, gb, threadIdx.x, gB, A, KNNp,
                                               FPSp, W, nullptr, nullptr, Hout,
                                               nullptr, nullptr, partials);
  }
}

// launch7: fps2 segC || SG1 gemm2 (in-place BNA, max/min epilogue)
template <int F2N, int KD, int ND>
__global__ __launch_bounds__(256, 4) void fps2_gemm_kernel(
    int f2Blocks, const float* f2xyz, int* f2out, int f2nsel, int it0, int it1,
    float* dming2, int* farg2,
    const short* A, const short* W, const float* bnscale, const float* bnshift,
    float* mmax, float* mmin, float* partials) {
  extern __shared__ char smem[];
  const int bx = (int)blockIdx.x;
  if (bx < f2Blocks) {
    fps_seg_body<F2N, 256>(smem, bx, threadIdx.x, f2xyz, f2out, nullptr, f2nsel,
                           it0, it1, dming2, farg2);
  } else {
    gemm_body<KD, ND, false, true, 1, 1, 1>(smem, bx - f2Blocks, threadIdx.x,
                                            (int)gridDim.x - f2Blocks, A, nullptr,
                                            nullptr, W, bnscale, bnshift, nullptr,
                                            mmax, mmin, partials);
  }
}

// standalone gemm; GATHER path gets bijective XCD swizzle (gridDim % 8 == 0)
template <int KD, int ND, bool GATHER, bool BNA, int NPTS, int S, int EPI>
__global__ __launch_bounds__(256, 4) void gemm_kernel(
    const short* A, const int* KNNp, const int* FPSp, const short* W,
    const float* bnscale, const float* bnshift, short* Hout,
    float* mmax, float* mmin, float* partials) {
  extern __shared__ char smem[];
  int bid = (int)blockIdx.x;
  if constexpr (GATHER) {
    const int q = (int)gridDim.x >> 3;
    bid = (bid & 7) * q + (bid >> 3);
  }
  gemm_body<KD, ND, GATHER, BNA, NPTS, S, EPI>(smem, bid, threadIdx.x,
                                               gridDim.x, A, KNNp, FPSp, W, bnscale,
                                               bnshift, Hout, mmax, mmin, partials);
}

// knn2 blocks first, then maxpool-f1 blocks (from mm1 max/min; 2 centers/block)
template <int NPTS, int S>
__global__ __launch_bounds__(256, 4) void maxpool_knn_kernel(
    int knnBlocks, const float* pts, const int* fpsidx, int* knn,
    const float* mmax, const float* mmin, const float* scale, const float* shift,
    short* f1) {
  __shared__ __align__(16) char smem[KNN_SMEM_BYTES];
  if ((int)blockIdx.x < knnBlocks) {
    knn_body<NPTS, S>(smem, blockIdx.x, threadIdx.x, pts, fpsidx, knn);
  } else {
    const int ctr = (blockIdx.x - knnBlocks) * 2 + (threadIdx.x >> 7);
    const int c = threadIdx.x & 127;
    const float sc = scale[c], sh = shift[c];
    float y = (sc >= 0.f) ? mmax[(size_t)ctr * 128 + c] : mmin[(size_t)ctr * 128 + c];
    f1[(size_t)ctr * 128 + c] = f2h(fmaxf(sc * y + sh, 0.f));
  }
}

// ---------- final: BN+ReLU on per-center max/min, transposed fp32 out ----------
__global__ __launch_bounds__(256) void maxpool_out_kernel(
    const float* __restrict__ mmax, const float* __restrict__ mmin,
    const float* __restrict__ scale, const float* __restrict__ shift,
    float* __restrict__ out) {
  const int bs = blockIdx.x, c = threadIdx.x;
  const int b = bs >> 8, s = bs & 255;
  const float sc = scale[c], sh = shift[c];
  float y = (sc >= 0.f) ? mmax[(size_t)bs * 256 + c] : mmin[(size_t)bs * 256 + c];
  out[((size_t)b << 16) + ((size_t)c << 8) + s] = fmaxf(sc * y + sh, 0.f);
}

// ---------- launch ----------
extern "C" void kernel_launch(void* const* d_in, const int* in_sizes, int n_in,
                              void* d_out, int out_size, void* d_ws, size_t ws_size,
                              hipStream_t stream) {
  (void)in_sizes; (void)n_in; (void)out_size; (void)ws_size;
  const float* x    = (const float*)d_in[0];
  const float* w1   = (const float*)d_in[1];
  const float* g1   = (const float*)d_in[2];
  const float* b1   = (const float*)d_in[3];
  const float* w2   = (const float*)d_in[4];
  const float* g2   = (const float*)d_in[5];
  const float* b2   = (const float*)d_in[6];
  const float* s1w1 = (const float*)d_in[7];
  const float* s1g1 = (const float*)d_in[8];
  const float* s1b1 = (const float*)d_in[9];
  const float* s1w2 = (const float*)d_in[10];
  const float* s1g2 = (const float*)d_in[11];
  const float* s1b2 = (const float*)d_in[12];
  const float* s2w1 = (const float*)d_in[13];
  const float* s2g1 = (const float*)d_in[14];
  const float* s2b1 = (const float*)d_in[15];
  const float* s2w2 = (const float*)d_in[16];
  const float* s2g2 = (const float*)d_in[17];
  const float* s2b2 = (const float*)d_in[18];
  float* out = (float*)d_out;

  char* ws = (char*)d_ws;
  size_t off = 0;
  auto alloc = [&](size_t bytes) -> char* {
    size_t p = (off + 255) & ~(size_t)255;
    off = p + bytes;
    return ws + p;
  };

  float* xyz      = (float*)alloc(32ull * 4096 * 3 * 4);
  short* h0       = (short*)alloc(32ull * 4096 * 64 * 2);
  short* hb       = (short*)alloc(32ull * 4096 * 64 * 2);
  short* fb       = (short*)alloc(32ull * 4096 * 64 * 2);
  int*   fps1     = (int*)alloc(32ull * 512 * 4);
  float* xyzc1    = (float*)alloc(32ull * 512 * 3 * 4);
  int*   knn1     = (int*)alloc(32ull * 512 * 32 * 4);
  short* f1       = (short*)alloc(32ull * 512 * 128 * 2);
  int*   fps2     = (int*)alloc(32ull * 256 * 4);
  int*   knn2     = (int*)alloc(32ull * 256 * 32 * 4);
  float* dming    = (float*)alloc(32ull * 4096 * 4);     // fps1 segment state
  int*   farg     = (int*)alloc(32 * 4);
  float* dming2   = (float*)alloc(32ull * 512 * 4);      // fps2 segment state
  int*   farg2    = (int*)alloc(32 * 4);
  short* hbuf     = (short*)alloc(134217728ull);          // shared SG1/SG2 h buffer
  float* mm1max   = (float*)alloc(16384ull * 128 * 4);    // SG1 per-center max/min
  float* mm1min   = (float*)alloc(16384ull * 128 * 4);
  float* mm2max   = (float*)alloc(8192ull * 256 * 4);     // SG2 per-center max/min
  float* mm2min   = (float*)alloc(8192ull * 256 * 4);
  float* partials = (float*)alloc(2ull * 256 * 4096 * 4); // 8 MB
  float* scA  = (float*)alloc(64 * 4);  float* shA  = (float*)alloc(64 * 4);
  float* scBc = (float*)alloc(64 * 4);  float* shBc = (float*)alloc(64 * 4);
  float* sc1a = (float*)alloc(128 * 4); float* sh1a = (float*)alloc(128 * 4);
  float* sc1b = (float*)alloc(128 * 4); float* sh1b = (float*)alloc(128 * 4);
  float* sc2a = (float*)alloc(256 * 4); float* sh2a = (float*)alloc(256 * 4);
  float* sc2b = (float*)alloc(256 * 4); float* sh2b = (float*)alloc(256 * 4);
  short* w2b   = (short*)alloc(4096 * 2);
  short* s1w2b = (short*)alloc(16384 * 2);
  short* s2w2b = (short*)alloc(65536 * 2);
  short* W1pp  = (short*)alloc(16384 * 2);
  short* W2pp  = (short*)alloc(65536 * 2);

  prep_kernel<<<656, 256, 0, stream>>>(w2, s1w2, s2w2, s1w1, s2w1, w2b, s1w2b, s2w2b, W1pp, W2pp);
  stageA_kernel<<<512, 256, 0, stream>>>(x, w1, xyz, h0);

  // fps1 in 4x128-iter segments; companions: MLP chain + knn1 chunks of the
  // centers emitted by PREVIOUS segments (knn[s] only needs fps1[s]).
  fps_stats_seg<4096, 256><<<288, 256, 49216, stream>>>(
      32, xyz, fps1, xyzc1, 512, 0, 128, dming, farg, h0, partials, 131072, 256);
  fps_r2_knn_seg<4096, 256, 4096, 512><<<4192, 256, 49216, stream>>>(
      32, 64, xyz, fps1, xyzc1, 512, 128, 256, dming, farg,
      partials, g1, b1, scA, shA, 256, 64, 1.f / 131072.f,
      xyz, fps1, knn1, 0);
  fps_gemm_knn_seg<4096, 256, 64, 64, true, 0, 4096, 512><<<5152, 256, 49216, stream>>>(
      32, 1024, xyz, fps1, xyzc1, 512, 256, 384, dming, farg,
      h0, w2b, scA, shA, hb, partials,
      xyz, fps1, knn1, 128);
  fps_r2_knn_seg<4096, 256, 4096, 512><<<4192, 256, 49216, stream>>>(
      32, 64, xyz, fps1, xyzc1, 512, 384, 512, dming, farg,
      partials, g2, b2, scBc, shBc, 1024, 64, 1.f / 131072.f,
      xyz, fps1, knn1, 256);

  // launch5: fps2 segA [0,86) || knn1 tail [384,512) || BN apply -> fb
  fps2_knn_apply_kernel<512, 4096, 512><<<8224, 256, 0, stream>>>(
      32, xyzc1, fps2, 256, 0, 86, dming2, farg2,
      4096, xyz, fps1, knn1, 384, hb, fb, scBc, shBc);

  // launch6: fps2 segB [86,171) || SG1 gemm1 (gather, swizzle)
  mega1_kernel<512, 128, 128, 4096, 512><<<4128, 256, 35840, stream>>>(
      32, xyzc1, fps2, 256, 86, 171, dming2, farg2,
      fb, knn1, fps1, W1pp, hbuf, partials);
  reduce2_kernel<<<128, 256, 0, stream>>>(partials, s1g1, s1b1, sc1a, sh1a, 4096, 128, 1.f / 524288.f);

  // launch7: fps2 segC [171,256) || SG1 gemm2 (in-place BNA, max/min -> mm1)
  fps2_gemm_kernel<512, 128, 128><<<4128, 256, 35840, stream>>>(
      32, xyzc1, fps2, 256, 171, 256, dming2, farg2,
      hbuf, s1w2b, sc1a, sh1a, mm1max, mm1min, partials);
  reduce2_kernel<<<128, 256, 0, stream>>>(partials, s1g2, s1b2, sc1b, sh1b, 4096, 128, 1.f / 524288.f);

  // knn2 (8192 blocks) || maxpool_f1 from mm1 (8192 blocks, 2 centers each)
  maxpool_knn_kernel<512, 256><<<16384, 256, 0, stream>>>(
      8192, xyzc1, fps2, knn2, mm1max, mm1min, sc1b, sh1b, f1);

  gemm_kernel<256, 256, true, false, 512, 256, 0><<<4096, 256, 38912, stream>>>(
      f1, knn2, fps2, W2pp, nullptr, nullptr, hbuf, nullptr, nullptr, partials);
  reduce2_kernel<<<256, 256, 0, stream>>>(partials, s2g1, s2b1, sc2a, sh2a, 4096, 256, 1.f / 262144.f);
  gemm_kernel<256, 256, false, true, 1, 1, 1><<<4096, 256, 38912, stream>>>(
      hbuf, nullptr, nullptr, s2w2b, sc2a, sh2a, nullptr, mm2max, mm2min, partials);
  reduce2_kernel<<<256, 256, 0, stream>>>(partials, s2g2, s2b2, sc2b, sh2b, 4096, 256, 1.f / 262144.f);
  maxpool_out_kernel<<<8192, 256, 0, stream>>>(mm2max, mm2min, sc2b, sh2b, out);
}